// Round 18
// baseline (1029.349 us; speedup 1.0000x reference)
//
#include <hip/hip_runtime.h>
#include <math.h>
#include <stdint.h>

// Problem constants (fixed by setup_inputs)
#define M     4096      // source rows
#define NTGT  65536     // target rows
#define KD    1024      // feature dim

// Screen tiling: 128x256 tile, 4 waves, i8 32x32x32 MFMA, fragment-ordered
// operands streamed global->registers; 3-set distance-2 register pipeline.
#define NS    32            // target slices
#define SLICE (NTGT / NS)   // 2048 targets per block
#define BT    128           // targets per tile
#define BS    256           // sources per block
#define NTILE (SLICE / BT)  // 16 target tiles per block
#define KC    32            // K=32 steps per tile (KD/32)
#define NCAND 256           // candidates per source row (NS * 8)
#define RESC  16            // rescore width (exact fp32)
// fragment-ordered tile: 32 rows x 1024 K int8 = [kc=0..31][lane=0..63][16B] = 32KB

typedef __attribute__((ext_vector_type(4)))  int i32x4;
typedef __attribute__((ext_vector_type(16))) int i32x16;

// ---------------------------------------------------------------------------
// helpers
// ---------------------------------------------------------------------------
__device__ __forceinline__ char f2i8(float x) {
    int t = __float2int_rn(x);
    t = t > 127 ? 127 : (t < -127 ? -127 : t);
    return (char)t;
}

template <int NK>
__device__ __forceinline__ void insert_desc_u(uint32_t (&arr)[NK], uint32_t pk) {
    uint32_t cur = pk;
#pragma unroll
    for (int s = 0; s < NK; ++s) {
        uint32_t old = arr[s];
        bool g = cur > old;
        arr[s] = g ? cur : old;
        cur    = g ? old : cur;
    }
}

// ---------------------------------------------------------------------------
// Prep A: per-target inverse norm (fp32, for rescore) + fragment-ordered int8
// of 1024*t-hat. Lane covers k = lane*16..+15 (coalesced 64B read); dest:
// tile g=row>>5, kc=lane>>1, h=lane&1, 16B at g*32768+(kc*64+(row&31)+32h)*16.
// ---------------------------------------------------------------------------
__global__ void prep_targets(const float* __restrict__ T, float* __restrict__ tinv,
                             char* __restrict__ TqF) {
    const int wave = threadIdx.x >> 6;
    const int lane = threadIdx.x & 63;
    const int row  = blockIdx.x * 4 + wave;
    const float* p = T + (size_t)row * KD + lane * 16;
    float4 v[4];
    float s = 0.f;
#pragma unroll
    for (int j = 0; j < 4; ++j) {
        v[j] = *reinterpret_cast<const float4*>(p + j * 4);
        s += v[j].x * v[j].x + v[j].y * v[j].y + v[j].z * v[j].z + v[j].w * v[j].w;
    }
#pragma unroll
    for (int off = 32; off; off >>= 1) s += __shfl_xor(s, off);
    const float rinv = 1.0f / sqrtf(fmaxf(s, 1e-24f));
    if (lane == 0) tinv[row] = rinv;
    const float sc = rinv * 1024.0f;
    unsigned char ob[16];
#pragma unroll
    for (int j = 0; j < 4; ++j) {
        ob[j * 4 + 0] = (unsigned char)f2i8(v[j].x * sc);
        ob[j * 4 + 1] = (unsigned char)f2i8(v[j].y * sc);
        ob[j * 4 + 2] = (unsigned char)f2i8(v[j].z * sc);
        ob[j * 4 + 3] = (unsigned char)f2i8(v[j].w * sc);
    }
    const int g = row >> 5, kc = lane >> 1, h = lane & 1;
    char* dst = TqF + (size_t)g * 32768 + (size_t)(kc * 64 + (row & 31) + 32 * h) * 16;
    *reinterpret_cast<uint4*>(dst) = *reinterpret_cast<const uint4*>(ob);
}

// Prep B: fragment-ordered int8 of 32*s (same layout, scale 32)
__global__ void prep_source(const float* __restrict__ S, char* __restrict__ SqF) {
    const int wave = threadIdx.x >> 6;
    const int lane = threadIdx.x & 63;
    const int row  = blockIdx.x * 4 + wave;
    const float* p = S + (size_t)row * KD + lane * 16;
    unsigned char ob[16];
#pragma unroll
    for (int j = 0; j < 4; ++j) {
        const float4 v = *reinterpret_cast<const float4*>(p + j * 4);
        ob[j * 4 + 0] = (unsigned char)f2i8(v.x * 32.0f);
        ob[j * 4 + 1] = (unsigned char)f2i8(v.y * 32.0f);
        ob[j * 4 + 2] = (unsigned char)f2i8(v.z * 32.0f);
        ob[j * 4 + 3] = (unsigned char)f2i8(v.w * 32.0f);
    }
    const int g = row >> 5, kc = lane >> 1, h = lane & 1;
    char* dst = SqF + (size_t)g * 32768 + (size_t)(kc * 64 + (row & 31) + 32 * h) * 16;
    *reinterpret_cast<uint4*>(dst) = *reinterpret_cast<const uint4*>(ob);
}

// ---------------------------------------------------------------------------
// Screen: 128x256 int8 MFMA GEMM (32x32x32), operands loaded per-fragment
// from global (fragment-ordered, 1KB coalesced per load, L1/L2-resident).
// 256 threads = 4 waves (wc = source quarter); per wave 128 targets x 64
// sources = acc[4][2] i32x16 (128 AGPRs). 3-set distance-2 register pipeline:
// at step kc, load step kc+2 into set (kc+2)%3 and compute set kc%3 — the
// per-tile K-loop is FULLY UNROLLED so %3 set selection constant-folds to
// named register sets (3 x 24 = 72 VGPR; ~115 VGPR + 128 AGPR <= 256-reg
// budget at 2 waves/SIMD). ~2 steps (~150-200cy) of L2-latency cover vs
// R16's 1-step E/O (the 400us invariant). No LDS, no barriers.
// ---------------------------------------------------------------------------
__global__ __launch_bounds__(256, 2)
void screen_kernel(const char* __restrict__ SqF, const char* __restrict__ TqF,
                   uint32_t* __restrict__ cand_out) {
    const int tid  = threadIdx.x;
    const int lane = tid & 63, wc = tid >> 6;
    const int l31 = lane & 31, l5 = lane >> 5;
    const int bx = blockIdx.x;           // source block (fastest)
    const int by = blockIdx.y;           // target slice
    const int sb   = bx * BS;
    const int tgt0 = by * SLICE;

    const char* pa = TqF + (size_t)(tgt0 >> 5) * 32768 + lane * 16;
    const char* pb = SqF + (size_t)((sb >> 5) + wc * 2) * 32768 + lane * 16;

#define LOADF(A, B, tt_, kc_) do {                                             \
        const size_t ao_ = (size_t)(tt_) * 131072 + (size_t)(kc_) * 1024;      \
        const size_t bo_ = (size_t)(kc_) * 1024;                               \
        A[0] = *reinterpret_cast<const i32x4*>(pa + ao_);                      \
        A[1] = *reinterpret_cast<const i32x4*>(pa + ao_ + 32768);              \
        A[2] = *reinterpret_cast<const i32x4*>(pa + ao_ + 65536);              \
        A[3] = *reinterpret_cast<const i32x4*>(pa + ao_ + 98304);              \
        B[0] = *reinterpret_cast<const i32x4*>(pb + bo_);                      \
        B[1] = *reinterpret_cast<const i32x4*>(pb + bo_ + 32768);              \
    } while (0)

#define MFMA8(A, B) do {                                                       \
        _Pragma("unroll")                                                      \
        for (int m = 0; m < 4; ++m)                                            \
            _Pragma("unroll")                                                  \
            for (int nt = 0; nt < 2; ++nt)                                     \
                acc[m][nt] = __builtin_amdgcn_mfma_i32_32x32x32_i8(            \
                    A[m], B[nt], acc[m][nt], 0, 0, 0);                         \
    } while (0)

    uint32_t cand[2][8];
#pragma unroll
    for (int nt = 0; nt < 2; ++nt)
#pragma unroll
        for (int j = 0; j < 8; ++j) cand[nt][j] = 0u;

    // 3 named fragment sets (distance-2 pipeline)
    i32x4 a0[4], b0[2], a1[4], b1[2], a2[4], b2[2];

#pragma unroll 1
    for (int tt = 0; tt < NTILE; ++tt) {
        i32x16 acc[4][2];
#pragma unroll
        for (int m = 0; m < 4; ++m)
#pragma unroll
            for (int nt = 0; nt < 2; ++nt)
                acc[m][nt] = (i32x16){0,0,0,0, 0,0,0,0, 0,0,0,0, 0,0,0,0};

        // per-tile prologue: steps 0 (set0) and 1 (set1)
        LOADF(a0, b0, tt, 0);
        LOADF(a1, b1, tt, 1);

#pragma unroll
        for (int kc = 0; kc < KC; ++kc) {
            if (kc + 2 < KC) {
                const int ls = (kc + 2) % 3;           // constant-folds (full unroll)
                if      (ls == 0) LOADF(a0, b0, tt, kc + 2);
                else if (ls == 1) LOADF(a1, b1, tt, kc + 2);
                else              LOADF(a2, b2, tt, kc + 2);
            }
            const int cs = kc % 3;                     // constant-folds
            if      (cs == 0) MFMA8(a0, b0);
            else if (cs == 1) MFMA8(a1, b1);
            else              MFMA8(a2, b2);
        }

        // screening scan. C layout (m101-verified): col = lane&31 (source),
        // row = (reg&3) + 8*(reg>>2) + 4*(lane>>5) (target within 32-tile).
        const int tb = tgt0 + tt * BT;
#pragma unroll
        for (int nt = 0; nt < 2; ++nt) {
            uint32_t c7 = cand[nt][7];
#pragma unroll
            for (int m = 0; m < 4; ++m) {
#pragma unroll
                for (int r = 0; r < 16; ++r) {
                    const int sc = acc[m][nt][r];
                    int k = (sc + (1 << 20)) >> 5;
                    k = k < 0 ? 0 : (k > 65535 ? 65535 : k);
                    const int tg = tb + m * 32 + (r & 3) + 8 * (r >> 2) + 4 * l5;
                    const uint32_t pk = ((uint32_t)k << 16) | (uint32_t)(tg & 0xFFFF);
                    if (pk > c7) {
                        insert_desc_u<8>(cand[nt], pk);
                        c7 = cand[nt][7];
                    }
                }
            }
        }
    }
#undef LOADF
#undef MFMA8

    // ---- candidate merge: 2 owner lanes per source (l5=0,1) -> l5=0; the
    // result IS the per-(slice,source) top-8 (single wave-row per strip).
#pragma unroll
    for (int nt = 0; nt < 2; ++nt) {
        uint32_t inc[8];
#pragma unroll
        for (int j = 0; j < 8; ++j)
            inc[j] = (uint32_t)__shfl_down((int)cand[nt][j], 32);
        if (lane < 32) {
#pragma unroll
            for (int j = 0; j < 8; ++j)
                if (inc[j] > cand[nt][7]) insert_desc_u<8>(cand[nt], inc[j]);
        }
    }

    if (lane < 32) {
#pragma unroll
        for (int nt = 0; nt < 2; ++nt) {
            const int src = sb + wc * 64 + nt * 32 + l31;
            uint32_t* dst = cand_out + (size_t)src * NCAND + by * 8;
            *reinterpret_cast<uint4*>(dst)     = make_uint4(cand[nt][0], cand[nt][1], cand[nt][2], cand[nt][3]);
            *reinterpret_cast<uint4*>(dst + 4) = make_uint4(cand[nt][4], cand[nt][5], cand[nt][6], cand[nt][7]);
        }
    }
}

// ---------------------------------------------------------------------------
// Final: wave-parallel top-16 selection of NCAND candidates -> exact fp32
// rescore -> top-4 -> gather + mean. One block (256 threads) per row.
// Packed keys are unique (target id in low 16 bits), so iterative wave-max
// extraction is exact.
// ---------------------------------------------------------------------------
__global__ __launch_bounds__(256)
void final_kernel(const uint32_t* __restrict__ cand_out, const float* __restrict__ S,
                  const float* __restrict__ T, const float* __restrict__ tinv,
                  float* __restrict__ out) {
    __shared__ __align__(16) float srow[KD];
    __shared__ float rv[RESC];
    __shared__ int   ri[RESC];
    __shared__ int   sel[4];

    const int r = blockIdx.x;
    const int tid = threadIdx.x;

    *reinterpret_cast<float4*>(srow + tid * 4) =
        *reinterpret_cast<const float4*>(S + (size_t)r * KD + tid * 4);

    if (tid < 64) {
        const uint4 cv = *reinterpret_cast<const uint4*>(cand_out + (size_t)r * NCAND + tid * 4);
        uint32_t c0 = cv.x, c1 = cv.y, c2 = cv.z, c3 = cv.w;
#pragma unroll 1
        for (int it = 0; it < RESC; ++it) {
            uint32_t m01 = c0 > c1 ? c0 : c1;
            uint32_t m23 = c2 > c3 ? c2 : c3;
            uint32_t m = m01 > m23 ? m01 : m23;
#pragma unroll
            for (int off = 32; off; off >>= 1) {
                const uint32_t o = (uint32_t)__shfl_xor((int)m, off);
                m = m > o ? m : o;
            }
            if (tid == 0) ri[it] = (int)(m & 0xFFFFu);
            if      (c0 == m) c0 = 0u;
            else if (c1 == m) c1 = 0u;
            else if (c2 == m) c2 = 0u;
            else if (c3 == m) c3 = 0u;
        }
    }
    __syncthreads();

    const int lane = tid & 63, wv = tid >> 6;
    for (int c = wv; c < RESC; c += 4) {
        const int idx = ri[c];
        const float* tp = T + (size_t)idx * KD;
        float s = 0.f;
#pragma unroll
        for (int j = 0; j < 4; ++j) {
            const float4 tv = *reinterpret_cast<const float4*>(tp + lane * 4 + j * 256);
            const float4 sv = *reinterpret_cast<const float4*>(srow + lane * 4 + j * 256);
            s += tv.x * sv.x + tv.y * sv.y + tv.z * sv.z + tv.w * sv.w;
        }
#pragma unroll
        for (int off = 32; off; off >>= 1) s += __shfl_xor(s, off);
        if (lane == 0) rv[c] = s * tinv[idx];
    }
    __syncthreads();

    if (tid == 0) {
        float b0 = -INFINITY, b1 = -INFINITY, b2 = -INFINITY, b3 = -INFINITY;
        int s0 = 0, s1 = 0, s2 = 0, s3 = 0;
        for (int c = 0; c < RESC; ++c) {
            const float v = rv[c]; const int id = ri[c];
            if (v > b3) {
                if (v > b0)      { b3=b2;s3=s2; b2=b1;s2=s1; b1=b0;s1=s0; b0=v;s0=id; }
                else if (v > b1) { b3=b2;s3=s2; b2=b1;s2=s1; b1=v;s1=id; }
                else if (v > b2) { b3=b2;s3=s2; b2=v;s2=id; }
                else             { b3=v;s3=id; }
            }
        }
        sel[0]=s0; sel[1]=s1; sel[2]=s2; sel[3]=s3;
    }
    __syncthreads();

    float4 a = make_float4(0.f, 0.f, 0.f, 0.f);
#pragma unroll
    for (int q = 0; q < 4; ++q) {
        const float4 v = *reinterpret_cast<const float4*>(T + (size_t)sel[q] * KD + tid * 4);
        a.x += v.x; a.y += v.y; a.z += v.z; a.w += v.w;
    }
    a.x *= 0.25f; a.y *= 0.25f; a.z *= 0.25f; a.w *= 0.25f;
    *reinterpret_cast<float4*>(out + (size_t)r * KD + tid * 4) = a;
}

// ===========================================================================
// Fallback (round-1 proven fp32 path) — used only if ws_size is too small.
// ===========================================================================
#define FNS    32
#define FSLICE (NTGT / FNS)
#define FBM 128
#define FBN 128
#define FBK 16
#define FNTILE (FSLICE / FBN)
#define FLDA 132
#define FLDSS 33

__global__ void tinv_kernel(const float* __restrict__ T, float* __restrict__ tinv) {
    const int wave = threadIdx.x >> 6;
    const int lane = threadIdx.x & 63;
    const int row  = blockIdx.x * 4 + wave;
    const float* p = T + (size_t)row * KD;
    float s = 0.f;
#pragma unroll
    for (int j = 0; j < 4; ++j) {
        float4 v = *reinterpret_cast<const float4*>(p + lane * 4 + j * 256);
        s += v.x * v.x + v.y * v.y + v.z * v.z + v.w * v.w;
    }
#pragma unroll
    for (int off = 32; off; off >>= 1) s += __shfl_xor(s, off);
    if (lane == 0) tinv[row] = 1.0f / sqrtf(fmaxf(s, 1e-24f));
}

__global__ __launch_bounds__(256, 2)
void simtopk_kernel(const float* __restrict__ S, const float* __restrict__ T,
                    const float* __restrict__ tinv,
                    float* __restrict__ pval, int* __restrict__ pidx) {
    __shared__ float smem[2 * FBK * FLDA];
    __shared__ float tinvS[FBN];
    float* As = smem;
    float* Bs = smem + FBK * FLDA;
    float* Ss = smem;

    const int tid = threadIdx.x;
    const int tx = tid & 15, ty = tid >> 4;
    const int rb   = blockIdx.x;
    const int tgt0 = blockIdx.y * FSLICE;
    const size_t abase = (size_t)(rb * FBM) * KD;

    float t0 = -INFINITY, t1 = -INFINITY, t2 = -INFINITY, t3 = -INFINITY;
    int   i0 = 0, i1 = 0, i2 = 0, i3 = 0;

    for (int nt = 0; nt < FNTILE; ++nt) {
        const int tb = tgt0 + nt * FBN;
        float acc[8][8];
#pragma unroll
        for (int i = 0; i < 8; ++i)
#pragma unroll
            for (int j = 0; j < 8; ++j) acc[i][j] = 0.f;

        for (int kk = 0; kk < KD; kk += FBK) {
            const int rr = tid >> 2;
            const int c4 = (tid & 3) * 4;
#pragma unroll
            for (int h = 0; h < 2; ++h) {
                const int row = rr + h * 64;
                float4 av = *reinterpret_cast<const float4*>(S + abase + (size_t)row * KD + kk + c4);
                float4 bv = *reinterpret_cast<const float4*>(T + (size_t)(tb + row) * KD + kk + c4);
                As[(c4 + 0) * FLDA + row] = av.x; As[(c4 + 1) * FLDA + row] = av.y;
                As[(c4 + 2) * FLDA + row] = av.z; As[(c4 + 3) * FLDA + row] = av.w;
                Bs[(c4 + 0) * FLDA + row] = bv.x; Bs[(c4 + 1) * FLDA + row] = bv.y;
                Bs[(c4 + 2) * FLDA + row] = bv.z; Bs[(c4 + 3) * FLDA + row] = bv.w;
            }
            __syncthreads();
#pragma unroll
            for (int k = 0; k < FBK; ++k) {
                float a[8], b[8];
                *reinterpret_cast<float4*>(&a[0]) = *reinterpret_cast<float4*>(&As[k * FLDA + ty * 8]);
                *reinterpret_cast<float4*>(&a[4]) = *reinterpret_cast<float4*>(&As[k * FLDA + ty * 8 + 4]);
                *reinterpret_cast<float4*>(&b[0]) = *reinterpret_cast<float4*>(&Bs[k * FLDA + tx * 4]);
                *reinterpret_cast<float4*>(&b[4]) = *reinterpret_cast<float4*>(&Bs[k * FLDA + 64 + tx * 4]);
#pragma unroll
                for (int i = 0; i < 8; ++i)
#pragma unroll
                    for (int j = 0; j < 8; ++j)
                        acc[i][j] = fmaf(a[i], b[j], acc[i][j]);
            }
            __syncthreads();
        }

        if (tid < FBN) tinvS[tid] = tinv[tb + tid];
        __syncthreads();

#pragma unroll
        for (int cc = 0; cc < 4; ++cc) {
            const int g = cc >> 1;
            if ((tx >> 3) == (cc & 1)) {
                const int txl = tx & 7;
#pragma unroll
                for (int i = 0; i < 8; ++i) {
                    const int rrow = ty * 8 + i;
#pragma unroll
                    for (int j = 0; j < 4; ++j) {
                        const int colc = 4 * txl + j;
                        Ss[rrow * FLDSS + colc] = acc[i][g * 4 + j] * tinvS[cc * 32 + colc];
                    }
                }
            }
            __syncthreads();
            if (tid < FBM) {
#pragma unroll 4
                for (int c = 0; c < 32; ++c) {
                    const float v = Ss[tid * FLDSS + c];
                    if (v > t3) {
                        const int gi = tb + cc * 32 + c;
                        if (v > t0)      { t3=t2;i3=i2; t2=t1;i2=i1; t1=t0;i1=i0; t0=v;i0=gi; }
                        else if (v > t1) { t3=t2;i3=i2; t2=t1;i2=i1; t1=v;i1=gi; }
                        else if (v > t2) { t3=t2;i3=i2; t2=v;i2=gi; }
                        else             { t3=v;i3=gi; }
                    }
                }
            }
            __syncthreads();
        }
    }

    if (tid < FBM) {
        const int row = rb * FBM + tid;
        const size_t base = ((size_t)blockIdx.y * M + row) * 4;
        pval[base + 0] = t0; pval[base + 1] = t1; pval[base + 2] = t2; pval[base + 3] = t3;
        pidx[base + 0] = i0; pidx[base + 1] = i1; pidx[base + 2] = i2; pidx[base + 3] = i3;
    }
}

__global__ void merge_kernel(const float* __restrict__ pval, const int* __restrict__ pidx,
                             const float* __restrict__ T, float* __restrict__ out) {
    __shared__ float cv[FNS * 4];
    __shared__ int   ci[FNS * 4];
    __shared__ int   sel[4];
    const int r = blockIdx.x;
    const int tid = threadIdx.x;

    if (tid < FNS * 4) {
        const int s = tid >> 2, q = tid & 3;
        const size_t base = ((size_t)s * M + r) * 4 + q;
        cv[tid] = pval[base];
        ci[tid] = pidx[base];
    }
    __syncthreads();

    if (tid == 0) {
        float t0 = -INFINITY, t1 = -INFINITY, t2 = -INFINITY, t3 = -INFINITY;
        int   j0 = 0, j1 = 0, j2 = 0, j3 = 0;
        for (int c = 0; c < FNS * 4; ++c) {
            const float v = cv[c];
            if (v > t3) {
                const int gi = ci[c];
                if (v > t0)      { t3=t2;j3=j2; t2=t1;j2=j1; t1=t0;j1=j0; t0=v;j0=gi; }
                else if (v > t1) { t3=t2;j3=j2; t2=t1;j2=j1; t1=v;j1=gi; }
                else if (v > t2) { t3=t2;j3=j2; t2=v;j2=gi; }
                else             { t3=v;j3=gi; }
            }
        }
        sel[0] = j0; sel[1] = j1; sel[2] = j2; sel[3] = j3;
    }
    __syncthreads();

    const int d = tid * 4;
    float4 a = make_float4(0.f, 0.f, 0.f, 0.f);
#pragma unroll
    for (int q = 0; q < 4; ++q) {
        const float4 v = *reinterpret_cast<const float4*>(T + (size_t)sel[q] * KD + d);
        a.x += v.x; a.y += v.y; a.z += v.z; a.w += v.w;
    }
    a.x *= 0.25f; a.y *= 0.25f; a.z *= 0.25f; a.w *= 0.25f;
    *reinterpret_cast<float4*>(out + (size_t)r * KD + d) = a;
}

// ---------------------------------------------------------------------------
extern "C" void kernel_launch(void* const* d_in, const int* in_sizes, int n_in,
                              void* d_out, int out_size, void* d_ws, size_t ws_size,
                              hipStream_t stream) {
    const float* S = (const float*)d_in[0];   // [4096,1024]
    const float* T = (const float*)d_in[1];   // [65536,1024]
    float* out = (float*)d_out;               // [4096,1024]

    const size_t sz_tinv = (size_t)NTGT * 4;                 // 256 KB
    const size_t sz_Sq   = (size_t)M * KD;                   // 4 MB
    const size_t sz_Tq   = (size_t)NTGT * KD;                // 64 MB
    const size_t sz_cand = (size_t)M * NCAND * 4;            // 4 MB
    const size_t need = sz_tinv + sz_Sq + sz_Tq + sz_cand;   // ~72.3 MB

    if (ws_size >= need) {
        float*    tinv = (float*)d_ws;
        char*     SqF  = (char*)d_ws + sz_tinv;
        char*     TqF  = (char*)d_ws + sz_tinv + sz_Sq;
        uint32_t* cand = (uint32_t*)((char*)d_ws + sz_tinv + sz_Sq + sz_Tq);

        prep_targets<<<NTGT / 4, 256, 0, stream>>>(T, tinv, TqF);
        prep_source<<<M / 4, 256, 0, stream>>>(S, SqF);
        screen_kernel<<<dim3(M / BS, NS), 256, 0, stream>>>(SqF, TqF, cand);
        final_kernel<<<M, 256, 0, stream>>>(cand, S, T, tinv, out);
    } else {
        // round-1 fp32 fallback (~7 ms, proven correct)
        float* tinv = (float*)d_ws;
        float* pval = tinv + NTGT;
        int*   pidx = (int*)(pval + (size_t)FNS * M * 4);

        tinv_kernel<<<NTGT / 4, 256, 0, stream>>>(T, tinv);
        simtopk_kernel<<<dim3(M / FBM, FNS), 256, 0, stream>>>(S, T, tinv, pval, pidx);
        merge_kernel<<<M, 256, 0, stream>>>(pval, pidx, T, out);
    }
}

// Round 19
// 523.342 us; speedup vs baseline: 1.9669x; 1.9669x over previous
//
#include <hip/hip_runtime.h>
#include <math.h>
#include <stdint.h>

// Problem constants (fixed by setup_inputs)
#define M     4096      // source rows
#define NTGT  65536     // target rows
#define KD    1024      // feature dim

// Screen tiling: 128x256 tile, 4 waves, i8 32x32x32 MFMA, fragment-ordered
// operands streamed global->registers; 3-set distance-2 register pipeline
// expressed as a COMPACT 3-body modular loop (R18's full unroll regressed:
// I-cache/scheduler blowup -> 993MB fetch; keep bodies static, trip runtime).
#define NS    32            // target slices
#define SLICE (NTGT / NS)   // 2048 targets per block
#define BT    128           // targets per tile
#define BS    256           // sources per block
#define NTILE (SLICE / BT)  // 16 target tiles per block
#define KC    32            // K=32 steps per tile (KD/32)
#define NCAND 256           // candidates per source row (NS * 8)
#define RESC  16            // rescore width (exact fp32)
// fragment-ordered tile: 32 rows x 1024 K int8 = [kc=0..31][lane=0..63][16B] = 32KB

typedef __attribute__((ext_vector_type(4)))  int i32x4;
typedef __attribute__((ext_vector_type(16))) int i32x16;

// ---------------------------------------------------------------------------
// helpers
// ---------------------------------------------------------------------------
__device__ __forceinline__ char f2i8(float x) {
    int t = __float2int_rn(x);
    t = t > 127 ? 127 : (t < -127 ? -127 : t);
    return (char)t;
}

template <int NK>
__device__ __forceinline__ void insert_desc_u(uint32_t (&arr)[NK], uint32_t pk) {
    uint32_t cur = pk;
#pragma unroll
    for (int s = 0; s < NK; ++s) {
        uint32_t old = arr[s];
        bool g = cur > old;
        arr[s] = g ? cur : old;
        cur    = g ? old : cur;
    }
}

// ---------------------------------------------------------------------------
// Prep A: per-target inverse norm (fp32, for rescore) + fragment-ordered int8
// of 1024*t-hat. Lane covers k = lane*16..+15 (coalesced 64B read); dest:
// tile g=row>>5, kc=lane>>1, h=lane&1, 16B at g*32768+(kc*64+(row&31)+32h)*16.
// ---------------------------------------------------------------------------
__global__ void prep_targets(const float* __restrict__ T, float* __restrict__ tinv,
                             char* __restrict__ TqF) {
    const int wave = threadIdx.x >> 6;
    const int lane = threadIdx.x & 63;
    const int row  = blockIdx.x * 4 + wave;
    const float* p = T + (size_t)row * KD + lane * 16;
    float4 v[4];
    float s = 0.f;
#pragma unroll
    for (int j = 0; j < 4; ++j) {
        v[j] = *reinterpret_cast<const float4*>(p + j * 4);
        s += v[j].x * v[j].x + v[j].y * v[j].y + v[j].z * v[j].z + v[j].w * v[j].w;
    }
#pragma unroll
    for (int off = 32; off; off >>= 1) s += __shfl_xor(s, off);
    const float rinv = 1.0f / sqrtf(fmaxf(s, 1e-24f));
    if (lane == 0) tinv[row] = rinv;
    const float sc = rinv * 1024.0f;
    unsigned char ob[16];
#pragma unroll
    for (int j = 0; j < 4; ++j) {
        ob[j * 4 + 0] = (unsigned char)f2i8(v[j].x * sc);
        ob[j * 4 + 1] = (unsigned char)f2i8(v[j].y * sc);
        ob[j * 4 + 2] = (unsigned char)f2i8(v[j].z * sc);
        ob[j * 4 + 3] = (unsigned char)f2i8(v[j].w * sc);
    }
    const int g = row >> 5, kc = lane >> 1, h = lane & 1;
    char* dst = TqF + (size_t)g * 32768 + (size_t)(kc * 64 + (row & 31) + 32 * h) * 16;
    *reinterpret_cast<uint4*>(dst) = *reinterpret_cast<const uint4*>(ob);
}

// Prep B: fragment-ordered int8 of 32*s (same layout, scale 32)
__global__ void prep_source(const float* __restrict__ S, char* __restrict__ SqF) {
    const int wave = threadIdx.x >> 6;
    const int lane = threadIdx.x & 63;
    const int row  = blockIdx.x * 4 + wave;
    const float* p = S + (size_t)row * KD + lane * 16;
    unsigned char ob[16];
#pragma unroll
    for (int j = 0; j < 4; ++j) {
        const float4 v = *reinterpret_cast<const float4*>(p + j * 4);
        ob[j * 4 + 0] = (unsigned char)f2i8(v.x * 32.0f);
        ob[j * 4 + 1] = (unsigned char)f2i8(v.y * 32.0f);
        ob[j * 4 + 2] = (unsigned char)f2i8(v.z * 32.0f);
        ob[j * 4 + 3] = (unsigned char)f2i8(v.w * 32.0f);
    }
    const int g = row >> 5, kc = lane >> 1, h = lane & 1;
    char* dst = SqF + (size_t)g * 32768 + (size_t)(kc * 64 + (row & 31) + 32 * h) * 16;
    *reinterpret_cast<uint4*>(dst) = *reinterpret_cast<const uint4*>(ob);
}

// ---------------------------------------------------------------------------
// Screen: 128x256 int8 MFMA GEMM (32x32x32), operands loaded per-fragment
// from global (fragment-ordered, 1KB coalesced per load, L1/L2-resident).
// 256 threads = 4 waves (wc = source quarter); per wave 128 targets x 64
// sources = acc[4][2] i32x16 (128 AGPRs). Distance-2 pipeline, 3 named sets,
// 3-body modular loop (static set names, runtime trip count -> compact code):
//   body: load s2<-b+2 | mfma s0(b) | load s0<-b+3 | mfma s1(b+1) |
//         load s1<-b+4 | mfma s2(b+2)        (b = 0,3,...,27)
// tail: mfma s0(30), mfma s1(31)  [loaded in the b=27 body; residues check].
// ~16 MFMA (~200cy) load->use cover vs R16 E/O's ~8. No LDS, no barriers.
// ---------------------------------------------------------------------------
__global__ __launch_bounds__(256, 2)
void screen_kernel(const char* __restrict__ SqF, const char* __restrict__ TqF,
                   uint32_t* __restrict__ cand_out) {
    const int tid  = threadIdx.x;
    const int lane = tid & 63, wc = tid >> 6;
    const int l31 = lane & 31, l5 = lane >> 5;
    const int bx = blockIdx.x;           // source block (fastest)
    const int by = blockIdx.y;           // target slice
    const int sb   = bx * BS;
    const int tgt0 = by * SLICE;

    const char* pa = TqF + (size_t)(tgt0 >> 5) * 32768 + lane * 16;
    const char* pb = SqF + (size_t)((sb >> 5) + wc * 2) * 32768 + lane * 16;

#define LOADF(A, B, tt_, kc_) do {                                             \
        const size_t ao_ = (size_t)(tt_) * 131072 + (size_t)(kc_) * 1024;      \
        const size_t bo_ = (size_t)(kc_) * 1024;                               \
        A[0] = *reinterpret_cast<const i32x4*>(pa + ao_);                      \
        A[1] = *reinterpret_cast<const i32x4*>(pa + ao_ + 32768);              \
        A[2] = *reinterpret_cast<const i32x4*>(pa + ao_ + 65536);              \
        A[3] = *reinterpret_cast<const i32x4*>(pa + ao_ + 98304);              \
        B[0] = *reinterpret_cast<const i32x4*>(pb + bo_);                      \
        B[1] = *reinterpret_cast<const i32x4*>(pb + bo_ + 32768);              \
    } while (0)

#define MFMA8(A, B) do {                                                       \
        _Pragma("unroll")                                                      \
        for (int m = 0; m < 4; ++m)                                            \
            _Pragma("unroll")                                                  \
            for (int nt = 0; nt < 2; ++nt)                                     \
                acc[m][nt] = __builtin_amdgcn_mfma_i32_32x32x32_i8(            \
                    A[m], B[nt], acc[m][nt], 0, 0, 0);                         \
    } while (0)

    uint32_t cand[2][8];
#pragma unroll
    for (int nt = 0; nt < 2; ++nt)
#pragma unroll
        for (int j = 0; j < 8; ++j) cand[nt][j] = 0u;

    // 3 named fragment sets (distance-2 pipeline)
    i32x4 a0[4], b0[2], a1[4], b1[2], a2[4], b2[2];

#pragma unroll 1
    for (int tt = 0; tt < NTILE; ++tt) {
        i32x16 acc[4][2];
#pragma unroll
        for (int m = 0; m < 4; ++m)
#pragma unroll
            for (int nt = 0; nt < 2; ++nt)
                acc[m][nt] = (i32x16){0,0,0,0, 0,0,0,0, 0,0,0,0, 0,0,0,0};

        // per-tile prologue: kc=0 -> s0, kc=1 -> s1
        LOADF(a0, b0, tt, 0);
        LOADF(a1, b1, tt, 1);

#pragma unroll 1
        for (int b = 0; b < 30; b += 3) {
            LOADF(a2, b2, tt, b + 2);
            MFMA8(a0, b0);                       // kc = b     (set 0)
            LOADF(a0, b0, tt, b + 3);
            MFMA8(a1, b1);                       // kc = b + 1 (set 1)
            LOADF(a1, b1, tt, b + 4);
            MFMA8(a2, b2);                       // kc = b + 2 (set 2)
        }
        // tail: kc=30 (in s0: 30%3==0), kc=31 (in s1: 31%3==1)
        MFMA8(a0, b0);
        MFMA8(a1, b1);

        // screening scan. C layout (m101-verified): col = lane&31 (source),
        // row = (reg&3) + 8*(reg>>2) + 4*(lane>>5) (target within 32-tile).
        const int tb = tgt0 + tt * BT;
#pragma unroll
        for (int nt = 0; nt < 2; ++nt) {
            uint32_t c7 = cand[nt][7];
#pragma unroll
            for (int m = 0; m < 4; ++m) {
#pragma unroll
                for (int r = 0; r < 16; ++r) {
                    const int sc = acc[m][nt][r];
                    int k = (sc + (1 << 20)) >> 5;
                    k = k < 0 ? 0 : (k > 65535 ? 65535 : k);
                    const int tg = tb + m * 32 + (r & 3) + 8 * (r >> 2) + 4 * l5;
                    const uint32_t pk = ((uint32_t)k << 16) | (uint32_t)(tg & 0xFFFF);
                    if (pk > c7) {
                        insert_desc_u<8>(cand[nt], pk);
                        c7 = cand[nt][7];
                    }
                }
            }
        }
    }
#undef LOADF
#undef MFMA8

    // ---- candidate merge: 2 owner lanes per source (l5=0,1) -> l5=0; the
    // result IS the per-(slice,source) top-8 (single wave-row per strip).
#pragma unroll
    for (int nt = 0; nt < 2; ++nt) {
        uint32_t inc[8];
#pragma unroll
        for (int j = 0; j < 8; ++j)
            inc[j] = (uint32_t)__shfl_down((int)cand[nt][j], 32);
        if (lane < 32) {
#pragma unroll
            for (int j = 0; j < 8; ++j)
                if (inc[j] > cand[nt][7]) insert_desc_u<8>(cand[nt], inc[j]);
        }
    }

    if (lane < 32) {
#pragma unroll
        for (int nt = 0; nt < 2; ++nt) {
            const int src = sb + wc * 64 + nt * 32 + l31;
            uint32_t* dst = cand_out + (size_t)src * NCAND + by * 8;
            *reinterpret_cast<uint4*>(dst)     = make_uint4(cand[nt][0], cand[nt][1], cand[nt][2], cand[nt][3]);
            *reinterpret_cast<uint4*>(dst + 4) = make_uint4(cand[nt][4], cand[nt][5], cand[nt][6], cand[nt][7]);
        }
    }
}

// ---------------------------------------------------------------------------
// Final: wave-parallel top-16 selection of NCAND candidates -> exact fp32
// rescore -> top-4 -> gather + mean. One block (256 threads) per row.
// Packed keys are unique (target id in low 16 bits), so iterative wave-max
// extraction is exact.
// ---------------------------------------------------------------------------
__global__ __launch_bounds__(256)
void final_kernel(const uint32_t* __restrict__ cand_out, const float* __restrict__ S,
                  const float* __restrict__ T, const float* __restrict__ tinv,
                  float* __restrict__ out) {
    __shared__ __align__(16) float srow[KD];
    __shared__ float rv[RESC];
    __shared__ int   ri[RESC];
    __shared__ int   sel[4];

    const int r = blockIdx.x;
    const int tid = threadIdx.x;

    *reinterpret_cast<float4*>(srow + tid * 4) =
        *reinterpret_cast<const float4*>(S + (size_t)r * KD + tid * 4);

    if (tid < 64) {
        const uint4 cv = *reinterpret_cast<const uint4*>(cand_out + (size_t)r * NCAND + tid * 4);
        uint32_t c0 = cv.x, c1 = cv.y, c2 = cv.z, c3 = cv.w;
#pragma unroll 1
        for (int it = 0; it < RESC; ++it) {
            uint32_t m01 = c0 > c1 ? c0 : c1;
            uint32_t m23 = c2 > c3 ? c2 : c3;
            uint32_t m = m01 > m23 ? m01 : m23;
#pragma unroll
            for (int off = 32; off; off >>= 1) {
                const uint32_t o = (uint32_t)__shfl_xor((int)m, off);
                m = m > o ? m : o;
            }
            if (tid == 0) ri[it] = (int)(m & 0xFFFFu);
            if      (c0 == m) c0 = 0u;
            else if (c1 == m) c1 = 0u;
            else if (c2 == m) c2 = 0u;
            else if (c3 == m) c3 = 0u;
        }
    }
    __syncthreads();

    const int lane = tid & 63, wv = tid >> 6;
    for (int c = wv; c < RESC; c += 4) {
        const int idx = ri[c];
        const float* tp = T + (size_t)idx * KD;
        float s = 0.f;
#pragma unroll
        for (int j = 0; j < 4; ++j) {
            const float4 tv = *reinterpret_cast<const float4*>(tp + lane * 4 + j * 256);
            const float4 sv = *reinterpret_cast<const float4*>(srow + lane * 4 + j * 256);
            s += tv.x * sv.x + tv.y * sv.y + tv.z * sv.z + tv.w * sv.w;
        }
#pragma unroll
        for (int off = 32; off; off >>= 1) s += __shfl_xor(s, off);
        if (lane == 0) rv[c] = s * tinv[idx];
    }
    __syncthreads();

    if (tid == 0) {
        float b0 = -INFINITY, b1 = -INFINITY, b2 = -INFINITY, b3 = -INFINITY;
        int s0 = 0, s1 = 0, s2 = 0, s3 = 0;
        for (int c = 0; c < RESC; ++c) {
            const float v = rv[c]; const int id = ri[c];
            if (v > b3) {
                if (v > b0)      { b3=b2;s3=s2; b2=b1;s2=s1; b1=b0;s1=s0; b0=v;s0=id; }
                else if (v > b1) { b3=b2;s3=s2; b2=b1;s2=s1; b1=v;s1=id; }
                else if (v > b2) { b3=b2;s3=s2; b2=v;s2=id; }
                else             { b3=v;s3=id; }
            }
        }
        sel[0]=s0; sel[1]=s1; sel[2]=s2; sel[3]=s3;
    }
    __syncthreads();

    float4 a = make_float4(0.f, 0.f, 0.f, 0.f);
#pragma unroll
    for (int q = 0; q < 4; ++q) {
        const float4 v = *reinterpret_cast<const float4*>(T + (size_t)sel[q] * KD + tid * 4);
        a.x += v.x; a.y += v.y; a.z += v.z; a.w += v.w;
    }
    a.x *= 0.25f; a.y *= 0.25f; a.z *= 0.25f; a.w *= 0.25f;
    *reinterpret_cast<float4*>(out + (size_t)r * KD + tid * 4) = a;
}

// ===========================================================================
// Fallback (round-1 proven fp32 path) — used only if ws_size is too small.
// ===========================================================================
#define FNS    32
#define FSLICE (NTGT / FNS)
#define FBM 128
#define FBN 128
#define FBK 16
#define FNTILE (FSLICE / FBN)
#define FLDA 132
#define FLDSS 33

__global__ void tinv_kernel(const float* __restrict__ T, float* __restrict__ tinv) {
    const int wave = threadIdx.x >> 6;
    const int lane = threadIdx.x & 63;
    const int row  = blockIdx.x * 4 + wave;
    const float* p = T + (size_t)row * KD;
    float s = 0.f;
#pragma unroll
    for (int j = 0; j < 4; ++j) {
        float4 v = *reinterpret_cast<const float4*>(p + lane * 4 + j * 256);
        s += v.x * v.x + v.y * v.y + v.z * v.z + v.w * v.w;
    }
#pragma unroll
    for (int off = 32; off; off >>= 1) s += __shfl_xor(s, off);
    if (lane == 0) tinv[row] = 1.0f / sqrtf(fmaxf(s, 1e-24f));
}

__global__ __launch_bounds__(256, 2)
void simtopk_kernel(const float* __restrict__ S, const float* __restrict__ T,
                    const float* __restrict__ tinv,
                    float* __restrict__ pval, int* __restrict__ pidx) {
    __shared__ float smem[2 * FBK * FLDA];
    __shared__ float tinvS[FBN];
    float* As = smem;
    float* Bs = smem + FBK * FLDA;
    float* Ss = smem;

    const int tid = threadIdx.x;
    const int tx = tid & 15, ty = tid >> 4;
    const int rb   = blockIdx.x;
    const int tgt0 = blockIdx.y * FSLICE;
    const size_t abase = (size_t)(rb * FBM) * KD;

    float t0 = -INFINITY, t1 = -INFINITY, t2 = -INFINITY, t3 = -INFINITY;
    int   i0 = 0, i1 = 0, i2 = 0, i3 = 0;

    for (int nt = 0; nt < FNTILE; ++nt) {
        const int tb = tgt0 + nt * FBN;
        float acc[8][8];
#pragma unroll
        for (int i = 0; i < 8; ++i)
#pragma unroll
            for (int j = 0; j < 8; ++j) acc[i][j] = 0.f;

        for (int kk = 0; kk < KD; kk += FBK) {
            const int rr = tid >> 2;
            const int c4 = (tid & 3) * 4;
#pragma unroll
            for (int h = 0; h < 2; ++h) {
                const int row = rr + h * 64;
                float4 av = *reinterpret_cast<const float4*>(S + abase + (size_t)row * KD + kk + c4);
                float4 bv = *reinterpret_cast<const float4*>(T + (size_t)(tb + row) * KD + kk + c4);
                As[(c4 + 0) * FLDA + row] = av.x; As[(c4 + 1) * FLDA + row] = av.y;
                As[(c4 + 2) * FLDA + row] = av.z; As[(c4 + 3) * FLDA + row] = av.w;
                Bs[(c4 + 0) * FLDA + row] = bv.x; Bs[(c4 + 1) * FLDA + row] = bv.y;
                Bs[(c4 + 2) * FLDA + row] = bv.z; Bs[(c4 + 3) * FLDA + row] = bv.w;
            }
            __syncthreads();
#pragma unroll
            for (int k = 0; k < FBK; ++k) {
                float a[8], b[8];
                *reinterpret_cast<float4*>(&a[0]) = *reinterpret_cast<float4*>(&As[k * FLDA + ty * 8]);
                *reinterpret_cast<float4*>(&a[4]) = *reinterpret_cast<float4*>(&As[k * FLDA + ty * 8 + 4]);
                *reinterpret_cast<float4*>(&b[0]) = *reinterpret_cast<float4*>(&Bs[k * FLDA + tx * 4]);
                *reinterpret_cast<float4*>(&b[4]) = *reinterpret_cast<float4*>(&Bs[k * FLDA + 64 + tx * 4]);
#pragma unroll
                for (int i = 0; i < 8; ++i)
#pragma unroll
                    for (int j = 0; j < 8; ++j)
                        acc[i][j] = fmaf(a[i], b[j], acc[i][j]);
            }
            __syncthreads();
        }

        if (tid < FBN) tinvS[tid] = tinv[tb + tid];
        __syncthreads();

#pragma unroll
        for (int cc = 0; cc < 4; ++cc) {
            const int g = cc >> 1;
            if ((tx >> 3) == (cc & 1)) {
                const int txl = tx & 7;
#pragma unroll
                for (int i = 0; i < 8; ++i) {
                    const int rrow = ty * 8 + i;
#pragma unroll
                    for (int j = 0; j < 4; ++j) {
                        const int colc = 4 * txl + j;
                        Ss[rrow * FLDSS + colc] = acc[i][g * 4 + j] * tinvS[cc * 32 + colc];
                    }
                }
            }
            __syncthreads();
            if (tid < FBM) {
#pragma unroll 4
                for (int c = 0; c < 32; ++c) {
                    const float v = Ss[tid * FLDSS + c];
                    if (v > t3) {
                        const int gi = tb + cc * 32 + c;
                        if (v > t0)      { t3=t2;i3=i2; t2=t1;i2=i1; t1=t0;i1=i0; t0=v;i0=gi; }
                        else if (v > t1) { t3=t2;i3=i2; t2=t1;i2=i1; t1=v;i1=gi; }
                        else if (v > t2) { t3=t2;i3=i2; t2=v;i2=gi; }
                        else             { t3=v;i3=gi; }
                    }
                }
            }
            __syncthreads();
        }
    }

    if (tid < FBM) {
        const int row = rb * FBM + tid;
        const size_t base = ((size_t)blockIdx.y * M + row) * 4;
        pval[base + 0] = t0; pval[base + 1] = t1; pval[base + 2] = t2; pval[base + 3] = t3;
        pidx[base + 0] = i0; pidx[base + 1] = i1; pidx[base + 2] = i2; pidx[base + 3] = i3;
    }
}

__global__ void merge_kernel(const float* __restrict__ pval, const int* __restrict__ pidx,
                             const float* __restrict__ T, float* __restrict__ out) {
    __shared__ float cv[FNS * 4];
    __shared__ int   ci[FNS * 4];
    __shared__ int   sel[4];
    const int r = blockIdx.x;
    const int tid = threadIdx.x;

    if (tid < FNS * 4) {
        const int s = tid >> 2, q = tid & 3;
        const size_t base = ((size_t)s * M + r) * 4 + q;
        cv[tid] = pval[base];
        ci[tid] = pidx[base];
    }
    __syncthreads();

    if (tid == 0) {
        float t0 = -INFINITY, t1 = -INFINITY, t2 = -INFINITY, t3 = -INFINITY;
        int   j0 = 0, j1 = 0, j2 = 0, j3 = 0;
        for (int c = 0; c < FNS * 4; ++c) {
            const float v = cv[c];
            if (v > t3) {
                const int gi = ci[c];
                if (v > t0)      { t3=t2;j3=j2; t2=t1;j2=j1; t1=t0;j1=j0; t0=v;j0=gi; }
                else if (v > t1) { t3=t2;j3=j2; t2=t1;j2=j1; t1=v;j1=gi; }
                else if (v > t2) { t3=t2;j3=j2; t2=v;j2=gi; }
                else             { t3=v;j3=gi; }
            }
        }
        sel[0] = j0; sel[1] = j1; sel[2] = j2; sel[3] = j3;
    }
    __syncthreads();

    const int d = tid * 4;
    float4 a = make_float4(0.f, 0.f, 0.f, 0.f);
#pragma unroll
    for (int q = 0; q < 4; ++q) {
        const float4 v = *reinterpret_cast<const float4*>(T + (size_t)sel[q] * KD + d);
        a.x += v.x; a.y += v.y; a.z += v.z; a.w += v.w;
    }
    a.x *= 0.25f; a.y *= 0.25f; a.z *= 0.25f; a.w *= 0.25f;
    *reinterpret_cast<float4*>(out + (size_t)r * KD + d) = a;
}

// ---------------------------------------------------------------------------
extern "C" void kernel_launch(void* const* d_in, const int* in_sizes, int n_in,
                              void* d_out, int out_size, void* d_ws, size_t ws_size,
                              hipStream_t stream) {
    const float* S = (const float*)d_in[0];   // [4096,1024]
    const float* T = (const float*)d_in[1];   // [65536,1024]
    float* out = (float*)d_out;               // [4096,1024]

    const size_t sz_tinv = (size_t)NTGT * 4;                 // 256 KB
    const size_t sz_Sq   = (size_t)M * KD;                   // 4 MB
    const size_t sz_Tq   = (size_t)NTGT * KD;                // 64 MB
    const size_t sz_cand = (size_t)M * NCAND * 4;            // 4 MB
    const size_t need = sz_tinv + sz_Sq + sz_Tq + sz_cand;   // ~72.3 MB

    if (ws_size >= need) {
        float*    tinv = (float*)d_ws;
        char*     SqF  = (char*)d_ws + sz_tinv;
        char*     TqF  = (char*)d_ws + sz_tinv + sz_Sq;
        uint32_t* cand = (uint32_t*)((char*)d_ws + sz_tinv + sz_Sq + sz_Tq);

        prep_targets<<<NTGT / 4, 256, 0, stream>>>(T, tinv, TqF);
        prep_source<<<M / 4, 256, 0, stream>>>(S, SqF);
        screen_kernel<<<dim3(M / BS, NS), 256, 0, stream>>>(SqF, TqF, cand);
        final_kernel<<<M, 256, 0, stream>>>(cand, S, T, tinv, out);
    } else {
        // round-1 fp32 fallback (~7 ms, proven correct)
        float* tinv = (float*)d_ws;
        float* pval = tinv + NTGT;
        int*   pidx = (int*)(pval + (size_t)FNS * M * 4);

        tinv_kernel<<<NTGT / 4, 256, 0, stream>>>(T, tinv);
        simtopk_kernel<<<dim3(M / FBM, FNS), 256, 0, stream>>>(S, T, tinv, pval, pidx);
        merge_kernel<<<M, 256, 0, stream>>>(pval, pidx, T, out);
    }
}

// Round 20
// 517.268 us; speedup vs baseline: 1.9900x; 1.0117x over previous
//
#include <hip/hip_runtime.h>
#include <math.h>
#include <stdint.h>

// Problem constants (fixed by setup_inputs)
#define M     4096      // source rows
#define NTGT  65536     // target rows
#define KD    1024      // feature dim

// Screen tiling: 128x256 tile, 4 waves, i8 32x32x32 MFMA, fragment-ordered
// operands streamed global->registers (no LDS, no barriers; R16-proven).
#define NS    32            // target slices
#define SLICE (NTGT / NS)   // 2048 targets per block
#define BT    128           // targets per tile
#define BS    256           // sources per block
#define NTILE (SLICE / BT)  // 16 target tiles per block
#define KC    32            // K=32 steps per tile (KD/32)
#define TOT   (NTILE * KC)  // 512 K-steps per block
#define NCAND 256           // candidates per source row (NS * 8)
#define RESC  16            // rescore width (exact fp32)
// fragment-ordered tile: 32 rows x 1024 K int8 = [kc=0..31][lane=0..63][16B] = 32KB

typedef __attribute__((ext_vector_type(4)))  int i32x4;
typedef __attribute__((ext_vector_type(16))) int i32x16;

// ---------------------------------------------------------------------------
// helpers
// ---------------------------------------------------------------------------
__device__ __forceinline__ char f2i8(float x) {
    int t = __float2int_rn(x);
    t = t > 127 ? 127 : (t < -127 ? -127 : t);
    return (char)t;
}

__device__ __forceinline__ int imax2(int a, int b) { return a > b ? a : b; }

template <int NK>
__device__ __forceinline__ void insert_desc_u(uint32_t (&arr)[NK], uint32_t pk) {
    uint32_t cur = pk;
#pragma unroll
    for (int s = 0; s < NK; ++s) {
        uint32_t old = arr[s];
        bool g = cur > old;
        arr[s] = g ? cur : old;
        cur    = g ? old : cur;
    }
}

// ---------------------------------------------------------------------------
// Prep A: per-target inverse norm (fp32, for rescore) + fragment-ordered int8
// of 1024*t-hat. Lane covers k = lane*16..+15 (coalesced 64B read); dest:
// tile g=row>>5, kc=lane>>1, h=lane&1, 16B at g*32768+(kc*64+(row&31)+32h)*16.
// ---------------------------------------------------------------------------
__global__ void prep_targets(const float* __restrict__ T, float* __restrict__ tinv,
                             char* __restrict__ TqF) {
    const int wave = threadIdx.x >> 6;
    const int lane = threadIdx.x & 63;
    const int row  = blockIdx.x * 4 + wave;
    const float* p = T + (size_t)row * KD + lane * 16;
    float4 v[4];
    float s = 0.f;
#pragma unroll
    for (int j = 0; j < 4; ++j) {
        v[j] = *reinterpret_cast<const float4*>(p + j * 4);
        s += v[j].x * v[j].x + v[j].y * v[j].y + v[j].z * v[j].z + v[j].w * v[j].w;
    }
#pragma unroll
    for (int off = 32; off; off >>= 1) s += __shfl_xor(s, off);
    const float rinv = 1.0f / sqrtf(fmaxf(s, 1e-24f));
    if (lane == 0) tinv[row] = rinv;
    const float sc = rinv * 1024.0f;
    unsigned char ob[16];
#pragma unroll
    for (int j = 0; j < 4; ++j) {
        ob[j * 4 + 0] = (unsigned char)f2i8(v[j].x * sc);
        ob[j * 4 + 1] = (unsigned char)f2i8(v[j].y * sc);
        ob[j * 4 + 2] = (unsigned char)f2i8(v[j].z * sc);
        ob[j * 4 + 3] = (unsigned char)f2i8(v[j].w * sc);
    }
    const int g = row >> 5, kc = lane >> 1, h = lane & 1;
    char* dst = TqF + (size_t)g * 32768 + (size_t)(kc * 64 + (row & 31) + 32 * h) * 16;
    *reinterpret_cast<uint4*>(dst) = *reinterpret_cast<const uint4*>(ob);
}

// Prep B: fragment-ordered int8 of 32*s (same layout, scale 32)
__global__ void prep_source(const float* __restrict__ S, char* __restrict__ SqF) {
    const int wave = threadIdx.x >> 6;
    const int lane = threadIdx.x & 63;
    const int row  = blockIdx.x * 4 + wave;
    const float* p = S + (size_t)row * KD + lane * 16;
    unsigned char ob[16];
#pragma unroll
    for (int j = 0; j < 4; ++j) {
        const float4 v = *reinterpret_cast<const float4*>(p + j * 4);
        ob[j * 4 + 0] = (unsigned char)f2i8(v.x * 32.0f);
        ob[j * 4 + 1] = (unsigned char)f2i8(v.y * 32.0f);
        ob[j * 4 + 2] = (unsigned char)f2i8(v.z * 32.0f);
        ob[j * 4 + 3] = (unsigned char)f2i8(v.w * 32.0f);
    }
    const int g = row >> 5, kc = lane >> 1, h = lane & 1;
    char* dst = SqF + (size_t)g * 32768 + (size_t)(kc * 64 + (row & 31) + 32 * h) * 16;
    *reinterpret_cast<uint4*>(dst) = *reinterpret_cast<const uint4*>(ob);
}

// ---------------------------------------------------------------------------
// Screen: 128x256 int8 MFMA GEMM (32x32x32), operands loaded per-fragment
// from global (fragment-ordered, 1KB coalesced per load, L1/L2-resident).
// 256 threads = 4 waves (wc = source quarter); per wave 128 targets x 64
// sources = acc[4][2] i32x16. Per K=32 step: 6 global_load_dwordx4 + 8 MFMA;
// E/O register double-buffer. Scan is gated by an integer max-reduce per
// 16-value block vs rawthr = ((c7>>16)<<5) - 2^20 (conservative superset of
// "could beat packed c7"), cutting common-path scan VALU ~8x (R16/R19
// counters: VALUBusy ~50% was co-binding with MFMA issue).
// ---------------------------------------------------------------------------
__global__ __launch_bounds__(256, 2)
void screen_kernel(const char* __restrict__ SqF, const char* __restrict__ TqF,
                   uint32_t* __restrict__ cand_out) {
    const int tid  = threadIdx.x;
    const int lane = tid & 63, wc = tid >> 6;
    const int l31 = lane & 31, l5 = lane >> 5;
    const int bx = blockIdx.x;           // source block (fastest)
    const int by = blockIdx.y;           // target slice
    const int sb   = bx * BS;
    const int tgt0 = by * SLICE;

    const char* pa = TqF + (size_t)(tgt0 >> 5) * 32768 + lane * 16;
    const char* pb = SqF + (size_t)((sb >> 5) + wc * 2) * 32768 + lane * 16;

#define LOADF(A, B, gs_) do {                                                  \
        const int tt_ = (gs_) >> 5, kc_ = (gs_) & 31;                          \
        const size_t ao_ = (size_t)tt_ * 131072 + (size_t)kc_ * 1024;          \
        const size_t bo_ = (size_t)kc_ * 1024;                                 \
        A[0] = *reinterpret_cast<const i32x4*>(pa + ao_);                      \
        A[1] = *reinterpret_cast<const i32x4*>(pa + ao_ + 32768);              \
        A[2] = *reinterpret_cast<const i32x4*>(pa + ao_ + 65536);              \
        A[3] = *reinterpret_cast<const i32x4*>(pa + ao_ + 98304);              \
        B[0] = *reinterpret_cast<const i32x4*>(pb + bo_);                      \
        B[1] = *reinterpret_cast<const i32x4*>(pb + bo_ + 32768);              \
    } while (0)

#define MFMA8(A, B) do {                                                       \
        _Pragma("unroll")                                                      \
        for (int m = 0; m < 4; ++m)                                            \
            _Pragma("unroll")                                                  \
            for (int nt = 0; nt < 2; ++nt)                                     \
                acc[m][nt] = __builtin_amdgcn_mfma_i32_32x32x32_i8(            \
                    A[m], B[nt], acc[m][nt], 0, 0, 0);                         \
    } while (0)

    uint32_t cand[2][8];
#pragma unroll
    for (int nt = 0; nt < 2; ++nt)
#pragma unroll
        for (int j = 0; j < 8; ++j) cand[nt][j] = 0u;
    int rawthr[2] = { -(1 << 20), -(1 << 20) };

    i32x4 aE[4], bE[2], aO[4], bO[2];
    LOADF(aE, bE, 0);

#pragma unroll 1
    for (int tt = 0; tt < NTILE; ++tt) {
        i32x16 acc[4][2];
#pragma unroll
        for (int m = 0; m < 4; ++m)
#pragma unroll
            for (int nt = 0; nt < 2; ++nt)
                acc[m][nt] = (i32x16){0,0,0,0, 0,0,0,0, 0,0,0,0, 0,0,0,0};

#pragma unroll 1
        for (int kcp = 0; kcp < KC / 2; ++kcp) {
            const int gs = tt * KC + kcp * 2;
            LOADF(aO, bO, gs + 1);           // gs+1 <= 511 always
            MFMA8(aE, bE);
            if (gs + 2 < TOT) LOADF(aE, bE, gs + 2);
            MFMA8(aO, bO);
        }

        // screening scan, max-gated. C layout (m101-verified): col = lane&31
        // (source), row = (reg&3) + 8*(reg>>2) + 4*(lane>>5).
        const int tb = tgt0 + tt * BT;
#pragma unroll
        for (int nt = 0; nt < 2; ++nt) {
#pragma unroll
            for (int m = 0; m < 4; ++m) {
                // integer max-tree over the 16 accumulator values
                int mx01 = imax2(acc[m][nt][0],  acc[m][nt][1]);
                int mx23 = imax2(acc[m][nt][2],  acc[m][nt][3]);
                int mx45 = imax2(acc[m][nt][4],  acc[m][nt][5]);
                int mx67 = imax2(acc[m][nt][6],  acc[m][nt][7]);
                int mx89 = imax2(acc[m][nt][8],  acc[m][nt][9]);
                int mxab = imax2(acc[m][nt][10], acc[m][nt][11]);
                int mxcd = imax2(acc[m][nt][12], acc[m][nt][13]);
                int mxef = imax2(acc[m][nt][14], acc[m][nt][15]);
                int mxa = imax2(imax2(mx01, mx23), imax2(mx45, mx67));
                int mxb = imax2(imax2(mx89, mxab), imax2(mxcd, mxef));
                if (imax2(mxa, mxb) < rawthr[nt]) continue;   // common path

                const int tgb = tb + m * 32 + 4 * l5;
                uint32_t c7 = cand[nt][7];
#pragma unroll
                for (int r = 0; r < 16; ++r) {
                    const int sc = acc[m][nt][r];
                    if (sc >= rawthr[nt]) {
                        int k = (sc + (1 << 20)) >> 5;
                        k = k < 0 ? 0 : (k > 65535 ? 65535 : k);
                        const int tg = tgb + (r & 3) + 8 * (r >> 2);
                        const uint32_t pk = ((uint32_t)k << 16) | (uint32_t)(tg & 0xFFFF);
                        if (pk > c7) {
                            insert_desc_u<8>(cand[nt], pk);
                            c7 = cand[nt][7];
                            rawthr[nt] = (((int)(c7 >> 16)) << 5) - (1 << 20);
                        }
                    }
                }
            }
        }
    }
#undef LOADF
#undef MFMA8

    // ---- candidate merge: 2 owner lanes per source (l5=0,1) -> l5=0; the
    // result IS the per-(slice,source) top-8 (single wave-row per strip).
#pragma unroll
    for (int nt = 0; nt < 2; ++nt) {
        uint32_t inc[8];
#pragma unroll
        for (int j = 0; j < 8; ++j)
            inc[j] = (uint32_t)__shfl_down((int)cand[nt][j], 32);
        if (lane < 32) {
#pragma unroll
            for (int j = 0; j < 8; ++j)
                if (inc[j] > cand[nt][7]) insert_desc_u<8>(cand[nt], inc[j]);
        }
    }

    if (lane < 32) {
#pragma unroll
        for (int nt = 0; nt < 2; ++nt) {
            const int src = sb + wc * 64 + nt * 32 + l31;
            uint32_t* dst = cand_out + (size_t)src * NCAND + by * 8;
            *reinterpret_cast<uint4*>(dst)     = make_uint4(cand[nt][0], cand[nt][1], cand[nt][2], cand[nt][3]);
            *reinterpret_cast<uint4*>(dst + 4) = make_uint4(cand[nt][4], cand[nt][5], cand[nt][6], cand[nt][7]);
        }
    }
}

// ---------------------------------------------------------------------------
// Final: wave-parallel top-16 selection of NCAND candidates -> exact fp32
// rescore -> top-4 -> gather + mean. One block (256 threads) per row.
// Packed keys are unique (target id in low 16 bits), so iterative wave-max
// extraction is exact.
// ---------------------------------------------------------------------------
__global__ __launch_bounds__(256)
void final_kernel(const uint32_t* __restrict__ cand_out, const float* __restrict__ S,
                  const float* __restrict__ T, const float* __restrict__ tinv,
                  float* __restrict__ out) {
    __shared__ __align__(16) float srow[KD];
    __shared__ float rv[RESC];
    __shared__ int   ri[RESC];
    __shared__ int   sel[4];

    const int r = blockIdx.x;
    const int tid = threadIdx.x;

    *reinterpret_cast<float4*>(srow + tid * 4) =
        *reinterpret_cast<const float4*>(S + (size_t)r * KD + tid * 4);

    if (tid < 64) {
        const uint4 cv = *reinterpret_cast<const uint4*>(cand_out + (size_t)r * NCAND + tid * 4);
        uint32_t c0 = cv.x, c1 = cv.y, c2 = cv.z, c3 = cv.w;
#pragma unroll 1
        for (int it = 0; it < RESC; ++it) {
            uint32_t m01 = c0 > c1 ? c0 : c1;
            uint32_t m23 = c2 > c3 ? c2 : c3;
            uint32_t m = m01 > m23 ? m01 : m23;
#pragma unroll
            for (int off = 32; off; off >>= 1) {
                const uint32_t o = (uint32_t)__shfl_xor((int)m, off);
                m = m > o ? m : o;
            }
            if (tid == 0) ri[it] = (int)(m & 0xFFFFu);
            if      (c0 == m) c0 = 0u;
            else if (c1 == m) c1 = 0u;
            else if (c2 == m) c2 = 0u;
            else if (c3 == m) c3 = 0u;
        }
    }
    __syncthreads();

    const int lane = tid & 63, wv = tid >> 6;
    for (int c = wv; c < RESC; c += 4) {
        const int idx = ri[c];
        const float* tp = T + (size_t)idx * KD;
        float s = 0.f;
#pragma unroll
        for (int j = 0; j < 4; ++j) {
            const float4 tv = *reinterpret_cast<const float4*>(tp + lane * 4 + j * 256);
            const float4 sv = *reinterpret_cast<const float4*>(srow + lane * 4 + j * 256);
            s += tv.x * sv.x + tv.y * sv.y + tv.z * sv.z + tv.w * sv.w;
        }
#pragma unroll
        for (int off = 32; off; off >>= 1) s += __shfl_xor(s, off);
        if (lane == 0) rv[c] = s * tinv[idx];
    }
    __syncthreads();

    if (tid == 0) {
        float b0 = -INFINITY, b1 = -INFINITY, b2 = -INFINITY, b3 = -INFINITY;
        int s0 = 0, s1 = 0, s2 = 0, s3 = 0;
        for (int c = 0; c < RESC; ++c) {
            const float v = rv[c]; const int id = ri[c];
            if (v > b3) {
                if (v > b0)      { b3=b2;s3=s2; b2=b1;s2=s1; b1=b0;s1=s0; b0=v;s0=id; }
                else if (v > b1) { b3=b2;s3=s2; b2=b1;s2=s1; b1=v;s1=id; }
                else if (v > b2) { b3=b2;s3=s2; b2=v;s2=id; }
                else             { b3=v;s3=id; }
            }
        }
        sel[0]=s0; sel[1]=s1; sel[2]=s2; sel[3]=s3;
    }
    __syncthreads();

    float4 a = make_float4(0.f, 0.f, 0.f, 0.f);
#pragma unroll
    for (int q = 0; q < 4; ++q) {
        const float4 v = *reinterpret_cast<const float4*>(T + (size_t)sel[q] * KD + tid * 4);
        a.x += v.x; a.y += v.y; a.z += v.z; a.w += v.w;
    }
    a.x *= 0.25f; a.y *= 0.25f; a.z *= 0.25f; a.w *= 0.25f;
    *reinterpret_cast<float4*>(out + (size_t)r * KD + tid * 4) = a;
}

// ===========================================================================
// Fallback (round-1 proven fp32 path) — used only if ws_size is too small.
// ===========================================================================
#define FNS    32
#define FSLICE (NTGT / FNS)
#define FBM 128
#define FBN 128
#define FBK 16
#define FNTILE (FSLICE / FBN)
#define FLDA 132
#define FLDSS 33

__global__ void tinv_kernel(const float* __restrict__ T, float* __restrict__ tinv) {
    const int wave = threadIdx.x >> 6;
    const int lane = threadIdx.x & 63;
    const int row  = blockIdx.x * 4 + wave;
    const float* p = T + (size_t)row * KD;
    float s = 0.f;
#pragma unroll
    for (int j = 0; j < 4; ++j) {
        float4 v = *reinterpret_cast<const float4*>(p + lane * 4 + j * 256);
        s += v.x * v.x + v.y * v.y + v.z * v.z + v.w * v.w;
    }
#pragma unroll
    for (int off = 32; off; off >>= 1) s += __shfl_xor(s, off);
    if (lane == 0) tinv[row] = 1.0f / sqrtf(fmaxf(s, 1e-24f));
}

__global__ __launch_bounds__(256, 2)
void simtopk_kernel(const float* __restrict__ S, const float* __restrict__ T,
                    const float* __restrict__ tinv,
                    float* __restrict__ pval, int* __restrict__ pidx) {
    __shared__ float smem[2 * FBK * FLDA];
    __shared__ float tinvS[FBN];
    float* As = smem;
    float* Bs = smem + FBK * FLDA;
    float* Ss = smem;

    const int tid = threadIdx.x;
    const int tx = tid & 15, ty = tid >> 4;
    const int rb   = blockIdx.x;
    const int tgt0 = blockIdx.y * FSLICE;
    const size_t abase = (size_t)(rb * FBM) * KD;

    float t0 = -INFINITY, t1 = -INFINITY, t2 = -INFINITY, t3 = -INFINITY;
    int   i0 = 0, i1 = 0, i2 = 0, i3 = 0;

    for (int nt = 0; nt < FNTILE; ++nt) {
        const int tb = tgt0 + nt * FBN;
        float acc[8][8];
#pragma unroll
        for (int i = 0; i < 8; ++i)
#pragma unroll
            for (int j = 0; j < 8; ++j) acc[i][j] = 0.f;

        for (int kk = 0; kk < KD; kk += FBK) {
            const int rr = tid >> 2;
            const int c4 = (tid & 3) * 4;
#pragma unroll
            for (int h = 0; h < 2; ++h) {
                const int row = rr + h * 64;
                float4 av = *reinterpret_cast<const float4*>(S + abase + (size_t)row * KD + kk + c4);
                float4 bv = *reinterpret_cast<const float4*>(T + (size_t)(tb + row) * KD + kk + c4);
                As[(c4 + 0) * FLDA + row] = av.x; As[(c4 + 1) * FLDA + row] = av.y;
                As[(c4 + 2) * FLDA + row] = av.z; As[(c4 + 3) * FLDA + row] = av.w;
                Bs[(c4 + 0) * FLDA + row] = bv.x; Bs[(c4 + 1) * FLDA + row] = bv.y;
                Bs[(c4 + 2) * FLDA + row] = bv.z; Bs[(c4 + 3) * FLDA + row] = bv.w;
            }
            __syncthreads();
#pragma unroll
            for (int k = 0; k < FBK; ++k) {
                float a[8], b[8];
                *reinterpret_cast<float4*>(&a[0]) = *reinterpret_cast<float4*>(&As[k * FLDA + ty * 8]);
                *reinterpret_cast<float4*>(&a[4]) = *reinterpret_cast<float4*>(&As[k * FLDA + ty * 8 + 4]);
                *reinterpret_cast<float4*>(&b[0]) = *reinterpret_cast<float4*>(&Bs[k * FLDA + tx * 4]);
                *reinterpret_cast<float4*>(&b[4]) = *reinterpret_cast<float4*>(&Bs[k * FLDA + 64 + tx * 4]);
#pragma unroll
                for (int i = 0; i < 8; ++i)
#pragma unroll
                    for (int j = 0; j < 8; ++j)
                        acc[i][j] = fmaf(a[i], b[j], acc[i][j]);
            }
            __syncthreads();
        }

        if (tid < FBN) tinvS[tid] = tinv[tb + tid];
        __syncthreads();

#pragma unroll
        for (int cc = 0; cc < 4; ++cc) {
            const int g = cc >> 1;
            if ((tx >> 3) == (cc & 1)) {
                const int txl = tx & 7;
#pragma unroll
                for (int i = 0; i < 8; ++i) {
                    const int rrow = ty * 8 + i;
#pragma unroll
                    for (int j = 0; j < 4; ++j) {
                        const int colc = 4 * txl + j;
                        Ss[rrow * FLDSS + colc] = acc[i][g * 4 + j] * tinvS[cc * 32 + colc];
                    }
                }
            }
            __syncthreads();
            if (tid < FBM) {
#pragma unroll 4
                for (int c = 0; c < 32; ++c) {
                    const float v = Ss[tid * FLDSS + c];
                    if (v > t3) {
                        const int gi = tb + cc * 32 + c;
                        if (v > t0)      { t3=t2;i3=i2; t2=t1;i2=i1; t1=t0;i1=i0; t0=v;i0=gi; }
                        else if (v > t1) { t3=t2;i3=i2; t2=t1;i2=i1; t1=v;i1=gi; }
                        else if (v > t2) { t3=t2;i3=i2; t2=v;i2=gi; }
                        else             { t3=v;i3=gi; }
                    }
                }
            }
            __syncthreads();
        }
    }

    if (tid < FBM) {
        const int row = rb * FBM + tid;
        const size_t base = ((size_t)blockIdx.y * M + row) * 4;
        pval[base + 0] = t0; pval[base + 1] = t1; pval[base + 2] = t2; pval[base + 3] = t3;
        pidx[base + 0] = i0; pidx[base + 1] = i1; pidx[base + 2] = i2; pidx[base + 3] = i3;
    }
}

__global__ void merge_kernel(const float* __restrict__ pval, const int* __restrict__ pidx,
                             const float* __restrict__ T, float* __restrict__ out) {
    __shared__ float cv[FNS * 4];
    __shared__ int   ci[FNS * 4];
    __shared__ int   sel[4];
    const int r = blockIdx.x;
    const int tid = threadIdx.x;

    if (tid < FNS * 4) {
        const int s = tid >> 2, q = tid & 3;
        const size_t base = ((size_t)s * M + r) * 4 + q;
        cv[tid] = pval[base];
        ci[tid] = pidx[base];
    }
    __syncthreads();

    if (tid == 0) {
        float t0 = -INFINITY, t1 = -INFINITY, t2 = -INFINITY, t3 = -INFINITY;
        int   j0 = 0, j1 = 0, j2 = 0, j3 = 0;
        for (int c = 0; c < FNS * 4; ++c) {
            const float v = cv[c];
            if (v > t3) {
                const int gi = ci[c];
                if (v > t0)      { t3=t2;j3=j2; t2=t1;j2=j1; t1=t0;j1=j0; t0=v;j0=gi; }
                else if (v > t1) { t3=t2;j3=j2; t2=t1;j2=j1; t1=v;j1=gi; }
                else if (v > t2) { t3=t2;j3=j2; t2=v;j2=gi; }
                else             { t3=v;j3=gi; }
            }
        }
        sel[0] = j0; sel[1] = j1; sel[2] = j2; sel[3] = j3;
    }
    __syncthreads();

    const int d = tid * 4;
    float4 a = make_float4(0.f, 0.f, 0.f, 0.f);
#pragma unroll
    for (int q = 0; q < 4; ++q) {
        const float4 v = *reinterpret_cast<const float4*>(T + (size_t)sel[q] * KD + d);
        a.x += v.x; a.y += v.y; a.z += v.z; a.w += v.w;
    }
    a.x *= 0.25f; a.y *= 0.25f; a.z *= 0.25f; a.w *= 0.25f;
    *reinterpret_cast<float4*>(out + (size_t)r * KD + d) = a;
}

// ---------------------------------------------------------------------------
extern "C" void kernel_launch(void* const* d_in, const int* in_sizes, int n_in,
                              void* d_out, int out_size, void* d_ws, size_t ws_size,
                              hipStream_t stream) {
    const float* S = (const float*)d_in[0];   // [4096,1024]
    const float* T = (const float*)d_in[1];   // [65536,1024]
    float* out = (float*)d_out;               // [4096,1024]

    const size_t sz_tinv = (size_t)NTGT * 4;                 // 256 KB
    const size_t sz_Sq   = (size_t)M * KD;                   // 4 MB
    const size_t sz_Tq   = (size_t)NTGT * KD;                // 64 MB
    const size_t sz_cand = (size_t)M * NCAND * 4;            // 4 MB
    const size_t need = sz_tinv + sz_Sq + sz_Tq + sz_cand;   // ~72.3 MB

    if (ws_size >= need) {
        float*    tinv = (float*)d_ws;
        char*     SqF  = (char*)d_ws + sz_tinv;
        char*     TqF  = (char*)d_ws + sz_tinv + sz_Sq;
        uint32_t* cand = (uint32_t*)((char*)d_ws + sz_tinv + sz_Sq + sz_Tq);

        prep_targets<<<NTGT / 4, 256, 0, stream>>>(T, tinv, TqF);
        prep_source<<<M / 4, 256, 0, stream>>>(S, SqF);
        screen_kernel<<<dim3(M / BS, NS), 256, 0, stream>>>(SqF, TqF, cand);
        final_kernel<<<M, 256, 0, stream>>>(cand, S, T, tinv, out);
    } else {
        // round-1 fp32 fallback (~7 ms, proven correct)
        float* tinv = (float*)d_ws;
        float* pval = tinv + NTGT;
        int*   pidx = (int*)(pval + (size_t)FNS * M * 4);

        tinv_kernel<<<NTGT / 4, 256, 0, stream>>>(T, tinv);
        simtopk_kernel<<<dim3(M / FBM, FNS), 256, 0, stream>>>(S, T, tinv, pval, pidx);
        merge_kernel<<<M, 256, 0, stream>>>(pval, pidx, T, out);
    }
}

// Round 21
// 475.467 us; speedup vs baseline: 2.1649x; 1.0879x over previous
//
#include <hip/hip_runtime.h>
#include <math.h>
#include <stdint.h>

// Problem constants (fixed by setup_inputs)
#define M     4096      // source rows
#define NTGT  65536     // target rows
#define KD    1024      // feature dim

// Screen tiling (R13-proven best): 128x256 tile, 4 waves, i8 32x32x32,
// K=64 steps, 48KB LDS -> 2 blocks/CU. acc[4][2] i32x16 = 128 regs -> max
// 2 waves/SIMD (R14: raising launch-bounds min-waves spills catastrophically).
#define NS    32            // target slices
#define SLICE (NTGT / NS)   // 2048 targets per block
#define BT    128           // targets per tile
#define BS    256           // sources per block
#define NTILE (SLICE / BT)  // 16 target tiles per block
#define TSTEP 16            // K-steps per tile (KD/64)
#define TOTST (NTILE * TSTEP) // 256 K-steps per block
#define NCAND 256           // candidates per source row (NS * 8)
#define RESC  16            // rescore width (exact fp32)
#define BUFSZ 24576         // one K-step buffer (A 8KB | B 16KB), int8

typedef __attribute__((ext_vector_type(4)))  int i32x4;
typedef __attribute__((ext_vector_type(16))) int i32x16;

// ---------------------------------------------------------------------------
// helpers
// ---------------------------------------------------------------------------
__device__ __forceinline__ char f2i8(float x) {
    int t = __float2int_rn(x);
    t = t > 127 ? 127 : (t < -127 ? -127 : t);
    return (char)t;
}

template <int NK>
__device__ __forceinline__ void insert_desc_u(uint32_t (&arr)[NK], uint32_t pk) {
    uint32_t cur = pk;
#pragma unroll
    for (int s = 0; s < NK; ++s) {
        uint32_t old = arr[s];
        bool g = cur > old;
        arr[s] = g ? cur : old;
        cur    = g ? old : cur;
    }
}

__device__ __forceinline__ void gload16(const void* g, void* l) {
    __builtin_amdgcn_global_load_lds(
        (const __attribute__((address_space(1))) unsigned int*)g,
        (__attribute__((address_space(3))) unsigned int*)l, 16, 0, 0);
}

// ---------------------------------------------------------------------------
// Prep A: per-target inverse norm (fp32, for rescore) + int8 of 1024*t-hat
// ---------------------------------------------------------------------------
__global__ void prep_targets(const float* __restrict__ T, float* __restrict__ tinv,
                             char* __restrict__ Tq) {
    const int wave = threadIdx.x >> 6;
    const int lane = threadIdx.x & 63;
    const int row  = blockIdx.x * 4 + wave;
    const float* p = T + (size_t)row * KD;
    float4 v[4];
    float s = 0.f;
#pragma unroll
    for (int j = 0; j < 4; ++j) {
        v[j] = *reinterpret_cast<const float4*>(p + lane * 4 + j * 256);
        s += v[j].x * v[j].x + v[j].y * v[j].y + v[j].z * v[j].z + v[j].w * v[j].w;
    }
#pragma unroll
    for (int off = 32; off; off >>= 1) s += __shfl_xor(s, off);
    const float rinv = 1.0f / sqrtf(fmaxf(s, 1e-24f));
    if (lane == 0) tinv[row] = rinv;
    const float sc = rinv * 1024.0f;
#pragma unroll
    for (int j = 0; j < 4; ++j) {
        char4 o;
        o.x = f2i8(v[j].x * sc); o.y = f2i8(v[j].y * sc);
        o.z = f2i8(v[j].z * sc); o.w = f2i8(v[j].w * sc);
        *reinterpret_cast<char4*>(Tq + (size_t)row * KD + lane * 4 + j * 256) = o;
    }
}

// Prep B: int8 of 32*s
__global__ void prep_source(const float* __restrict__ S, char* __restrict__ Sq) {
    const int wave = threadIdx.x >> 6;
    const int lane = threadIdx.x & 63;
    const int row  = blockIdx.x * 4 + wave;
    const float* p = S + (size_t)row * KD;
#pragma unroll
    for (int j = 0; j < 4; ++j) {
        float4 v = *reinterpret_cast<const float4*>(p + lane * 4 + j * 256);
        char4 o;
        o.x = f2i8(v.x * 32.0f); o.y = f2i8(v.y * 32.0f);
        o.z = f2i8(v.z * 32.0f); o.w = f2i8(v.w * 32.0f);
        *reinterpret_cast<char4*>(Sq + (size_t)row * KD + lane * 4 + j * 256) = o;
    }
}

// ---------------------------------------------------------------------------
// Screen (R13-proven, byte-identical): 128x256 int8 MFMA GEMM (32x32x32) +
// per-lane packed top-8 per source column. 256 threads = 4 waves, each 128
// targets x 64 sources (wc = source quarter); acc[4][2] i32x16 (AGPRs),
// 16 MFMA / 12 ds_read_b128 per step; 2 blocks/CU overlap LDS and matrix
// pipes across blocks. Per-slice top-8 final after l5 shuffle merge.
// Swizzle: chunk16 ^= (row>>1)&3 (write: pre-swizzled source; read: lane off).
// ---------------------------------------------------------------------------
__global__ __launch_bounds__(256, 2)
void screen_kernel(const char* __restrict__ Sq, const char* __restrict__ Tq,
                   uint32_t* __restrict__ cand_out) {
    __shared__ __align__(16) unsigned char lds[2 * BUFSZ];

    const int tid  = threadIdx.x;
    const int lane = tid & 63, wc = tid >> 6;
    const int l31 = lane & 31, l5 = lane >> 5;
    const int bx = blockIdx.x;           // source block (fastest)
    const int by = blockIdx.y;           // target slice
    const int sb   = bx * BS;
    const int tgt0 = by * SLICE;

    const int srow = tid >> 2;                            // 0..63
    const int scol = ((tid & 3) ^ ((tid >> 3) & 3)) * 16; // pre-swizzled byte off
    const char* aStage = Tq + (size_t)(tgt0 + srow) * KD + scol;
    const char* bStage = Sq + (size_t)(sb   + srow) * KD + scol;

    const int s3 = (l31 >> 1) & 3;
    int aOff0[4], aOff1[4], bOff0[2], bOff1[2];
#pragma unroll
    for (int m = 0; m < 4; ++m) {
        const int base = (m * 32 + l31) * 64;
        aOff0[m] = base + ((l5    ) ^ s3) * 16;
        aOff1[m] = base + ((2 + l5) ^ s3) * 16;
    }
#pragma unroll
    for (int nt = 0; nt < 2; ++nt) {
        const int base = 8192 + (wc * 64 + nt * 32 + l31) * 64;
        bOff0[nt] = base + ((l5    ) ^ s3) * 16;
        bOff1[nt] = base + ((2 + l5) ^ s3) * 16;
    }

#define BARX()  __builtin_amdgcn_s_barrier()
#define FENCE() asm volatile("" ::: "memory")
#define VM6()   asm volatile("s_waitcnt vmcnt(6)" ::: "memory")
#define VM0()   asm volatile("s_waitcnt vmcnt(0)" ::: "memory")

#define STAGE(s_) do {                                                         \
        const int tt_ = (s_) >> 4, ks_ = (s_) & 15;                            \
        unsigned char* d_ = lds + (((s_) & 1) ? BUFSZ : 0) + tid * 16;         \
        const char* a_ = aStage + (size_t)(tt_ * BT) * KD + ks_ * 64;          \
        const char* b_ = bStage + ks_ * 64;                                    \
        gload16(a_,            d_);                                            \
        gload16(a_ + 64 * KD,  d_ + 4096);                                     \
        gload16(b_,            d_ + 8192);                                     \
        gload16(b_ + 64 * KD,  d_ + 8192 + 4096);                              \
        gload16(b_ + 128 * KD, d_ + 8192 + 8192);                              \
        gload16(b_ + 192 * KD, d_ + 8192 + 12288);                             \
    } while (0)

    uint32_t cand[2][8];
#pragma unroll
    for (int nt = 0; nt < 2; ++nt)
#pragma unroll
        for (int j = 0; j < 8; ++j) cand[nt][j] = 0u;

    STAGE(0);

#pragma unroll 1
    for (int tt = 0; tt < NTILE; ++tt) {
        i32x16 acc[4][2];
#pragma unroll
        for (int m = 0; m < 4; ++m)
#pragma unroll
            for (int nt = 0; nt < 2; ++nt)
                acc[m][nt] = (i32x16){0,0,0,0, 0,0,0,0, 0,0,0,0, 0,0,0,0};

#pragma unroll 1
        for (int ks = 0; ks < TSTEP; ++ks) {
            const int s = tt * TSTEP + ks;
            if (s + 1 < TOTST) { STAGE(s + 1); VM6(); }
            else               { VM0(); }
            BARX(); FENCE();

            const unsigned char* cb = lds + ((s & 1) ? BUFSZ : 0);
            i32x4 a0[4], a1[4], b0[2], b1[2];
#pragma unroll
            for (int m = 0; m < 4; ++m) {
                a0[m] = *reinterpret_cast<const i32x4*>(cb + aOff0[m]);
                a1[m] = *reinterpret_cast<const i32x4*>(cb + aOff1[m]);
            }
#pragma unroll
            for (int nt = 0; nt < 2; ++nt) {
                b0[nt] = *reinterpret_cast<const i32x4*>(cb + bOff0[nt]);
                b1[nt] = *reinterpret_cast<const i32x4*>(cb + bOff1[nt]);
            }
#pragma unroll
            for (int m = 0; m < 4; ++m)
#pragma unroll
                for (int nt = 0; nt < 2; ++nt) {
                    acc[m][nt] = __builtin_amdgcn_mfma_i32_32x32x32_i8(a0[m], b0[nt], acc[m][nt], 0, 0, 0);
                    acc[m][nt] = __builtin_amdgcn_mfma_i32_32x32x32_i8(a1[m], b1[nt], acc[m][nt], 0, 0, 0);
                }

            FENCE(); BARX();
        }

        // screening scan. C layout (m101-verified): col = lane&31 (source),
        // row = (reg&3) + 8*(reg>>2) + 4*(lane>>5) (target within 32-tile).
        const int tb = tgt0 + tt * BT;
#pragma unroll
        for (int nt = 0; nt < 2; ++nt) {
            uint32_t c7 = cand[nt][7];
#pragma unroll
            for (int m = 0; m < 4; ++m) {
#pragma unroll
                for (int r = 0; r < 16; ++r) {
                    const int sc = acc[m][nt][r];
                    int k = (sc + (1 << 20)) >> 5;
                    k = k < 0 ? 0 : (k > 65535 ? 65535 : k);
                    const int tg = tb + m * 32 + (r & 3) + 8 * (r >> 2) + 4 * l5;
                    const uint32_t pk = ((uint32_t)k << 16) | (uint32_t)(tg & 0xFFFF);
                    if (pk > c7) {
                        insert_desc_u<8>(cand[nt], pk);
                        c7 = cand[nt][7];
                    }
                }
            }
        }
    }
#undef STAGE

    // ---- candidate merge: 2 owner lanes per source (l5=0,1) -> l5=0; the
    // result IS the per-(slice,source) top-8 (single wave-row per strip).
#pragma unroll
    for (int nt = 0; nt < 2; ++nt) {
        uint32_t inc[8];
#pragma unroll
        for (int j = 0; j < 8; ++j)
            inc[j] = (uint32_t)__shfl_down((int)cand[nt][j], 32);
        if (lane < 32) {
#pragma unroll
            for (int j = 0; j < 8; ++j)
                if (inc[j] > cand[nt][7]) insert_desc_u<8>(cand[nt], inc[j]);
        }
    }

    if (lane < 32) {
#pragma unroll
        for (int nt = 0; nt < 2; ++nt) {
            const int src = sb + wc * 64 + nt * 32 + l31;
            uint32_t* dst = cand_out + (size_t)src * NCAND + by * 8;
            *reinterpret_cast<uint4*>(dst)     = make_uint4(cand[nt][0], cand[nt][1], cand[nt][2], cand[nt][3]);
            *reinterpret_cast<uint4*>(dst + 4) = make_uint4(cand[nt][4], cand[nt][5], cand[nt][6], cand[nt][7]);
        }
    }
}

// ---------------------------------------------------------------------------
// Final: wave-parallel top-16 selection of NCAND candidates -> exact fp32
// rescore -> top-4 -> gather + mean. One block (256 threads) per row.
// Packed keys are unique (target id in low 16 bits), so iterative wave-max
// extraction is exact.
// ---------------------------------------------------------------------------
__global__ __launch_bounds__(256)
void final_kernel(const uint32_t* __restrict__ cand_out, const float* __restrict__ S,
                  const float* __restrict__ T, const float* __restrict__ tinv,
                  float* __restrict__ out) {
    __shared__ __align__(16) float srow[KD];
    __shared__ float rv[RESC];
    __shared__ int   ri[RESC];
    __shared__ int   sel[4];

    const int r = blockIdx.x;
    const int tid = threadIdx.x;

    *reinterpret_cast<float4*>(srow + tid * 4) =
        *reinterpret_cast<const float4*>(S + (size_t)r * KD + tid * 4);

    if (tid < 64) {
        const uint4 cv = *reinterpret_cast<const uint4*>(cand_out + (size_t)r * NCAND + tid * 4);
        uint32_t c0 = cv.x, c1 = cv.y, c2 = cv.z, c3 = cv.w;
#pragma unroll 1
        for (int it = 0; it < RESC; ++it) {
            uint32_t m01 = c0 > c1 ? c0 : c1;
            uint32_t m23 = c2 > c3 ? c2 : c3;
            uint32_t m = m01 > m23 ? m01 : m23;
#pragma unroll
            for (int off = 32; off; off >>= 1) {
                const uint32_t o = (uint32_t)__shfl_xor((int)m, off);
                m = m > o ? m : o;
            }
            if (tid == 0) ri[it] = (int)(m & 0xFFFFu);
            if      (c0 == m) c0 = 0u;
            else if (c1 == m) c1 = 0u;
            else if (c2 == m) c2 = 0u;
            else if (c3 == m) c3 = 0u;
        }
    }
    __syncthreads();

    const int lane = tid & 63, wv = tid >> 6;
    for (int c = wv; c < RESC; c += 4) {
        const int idx = ri[c];
        const float* tp = T + (size_t)idx * KD;
        float s = 0.f;
#pragma unroll
        for (int j = 0; j < 4; ++j) {
            const float4 tv = *reinterpret_cast<const float4*>(tp + lane * 4 + j * 256);
            const float4 sv = *reinterpret_cast<const float4*>(srow + lane * 4 + j * 256);
            s += tv.x * sv.x + tv.y * sv.y + tv.z * sv.z + tv.w * sv.w;
        }
#pragma unroll
        for (int off = 32; off; off >>= 1) s += __shfl_xor(s, off);
        if (lane == 0) rv[c] = s * tinv[idx];
    }
    __syncthreads();

    if (tid == 0) {
        float b0 = -INFINITY, b1 = -INFINITY, b2 = -INFINITY, b3 = -INFINITY;
        int s0 = 0, s1 = 0, s2 = 0, s3 = 0;
        for (int c = 0; c < RESC; ++c) {
            const float v = rv[c]; const int id = ri[c];
            if (v > b3) {
                if (v > b0)      { b3=b2;s3=s2; b2=b1;s2=s1; b1=b0;s1=s0; b0=v;s0=id; }
                else if (v > b1) { b3=b2;s3=s2; b2=b1;s2=s1; b1=v;s1=id; }
                else if (v > b2) { b3=b2;s3=s2; b2=v;s2=id; }
                else             { b3=v;s3=id; }
            }
        }
        sel[0]=s0; sel[1]=s1; sel[2]=s2; sel[3]=s3;
    }
    __syncthreads();

    float4 a = make_float4(0.f, 0.f, 0.f, 0.f);
#pragma unroll
    for (int q = 0; q < 4; ++q) {
        const float4 v = *reinterpret_cast<const float4*>(T + (size_t)sel[q] * KD + tid * 4);
        a.x += v.x; a.y += v.y; a.z += v.z; a.w += v.w;
    }
    a.x *= 0.25f; a.y *= 0.25f; a.z *= 0.25f; a.w *= 0.25f;
    *reinterpret_cast<float4*>(out + (size_t)r * KD + tid * 4) = a;
}

// ===========================================================================
// Fallback (round-1 proven fp32 path) — used only if ws_size is too small.
// ===========================================================================
#define FNS    32
#define FSLICE (NTGT / FNS)
#define FBM 128
#define FBN 128
#define FBK 16
#define FNTILE (FSLICE / FBN)
#define FLDA 132
#define FLDSS 33

__global__ void tinv_kernel(const float* __restrict__ T, float* __restrict__ tinv) {
    const int wave = threadIdx.x >> 6;
    const int lane = threadIdx.x & 63;
    const int row  = blockIdx.x * 4 + wave;
    const float* p = T + (size_t)row * KD;
    float s = 0.f;
#pragma unroll
    for (int j = 0; j < 4; ++j) {
        float4 v = *reinterpret_cast<const float4*>(p + lane * 4 + j * 256);
        s += v.x * v.x + v.y * v.y + v.z * v.z + v.w * v.w;
    }
#pragma unroll
    for (int off = 32; off; off >>= 1) s += __shfl_xor(s, off);
    if (lane == 0) tinv[row] = 1.0f / sqrtf(fmaxf(s, 1e-24f));
}

__global__ __launch_bounds__(256, 2)
void simtopk_kernel(const float* __restrict__ S, const float* __restrict__ T,
                    const float* __restrict__ tinv,
                    float* __restrict__ pval, int* __restrict__ pidx) {
    __shared__ float smem[2 * FBK * FLDA];
    __shared__ float tinvS[FBN];
    float* As = smem;
    float* Bs = smem + FBK * FLDA;
    float* Ss = smem;

    const int tid = threadIdx.x;
    const int tx = tid & 15, ty = tid >> 4;
    const int rb   = blockIdx.x;
    const int tgt0 = blockIdx.y * FSLICE;
    const size_t abase = (size_t)(rb * FBM) * KD;

    float t0 = -INFINITY, t1 = -INFINITY, t2 = -INFINITY, t3 = -INFINITY;
    int   i0 = 0, i1 = 0, i2 = 0, i3 = 0;

    for (int nt = 0; nt < FNTILE; ++nt) {
        const int tb = tgt0 + nt * FBN;
        float acc[8][8];
#pragma unroll
        for (int i = 0; i < 8; ++i)
#pragma unroll
            for (int j = 0; j < 8; ++j) acc[i][j] = 0.f;

        for (int kk = 0; kk < KD; kk += FBK) {
            const int rr = tid >> 2;
            const int c4 = (tid & 3) * 4;
#pragma unroll
            for (int h = 0; h < 2; ++h) {
                const int row = rr + h * 64;
                float4 av = *reinterpret_cast<const float4*>(S + abase + (size_t)row * KD + kk + c4);
                float4 bv = *reinterpret_cast<const float4*>(T + (size_t)(tb + row) * KD + kk + c4);
                As[(c4 + 0) * FLDA + row] = av.x; As[(c4 + 1) * FLDA + row] = av.y;
                As[(c4 + 2) * FLDA + row] = av.z; As[(c4 + 3) * FLDA + row] = av.w;
                Bs[(c4 + 0) * FLDA + row] = bv.x; Bs[(c4 + 1) * FLDA + row] = bv.y;
                Bs[(c4 + 2) * FLDA + row] = bv.z; Bs[(c4 + 3) * FLDA + row] = bv.w;
            }
            __syncthreads();
#pragma unroll
            for (int k = 0; k < FBK; ++k) {
                float a[8], b[8];
                *reinterpret_cast<float4*>(&a[0]) = *reinterpret_cast<float4*>(&As[k * FLDA + ty * 8]);
                *reinterpret_cast<float4*>(&a[4]) = *reinterpret_cast<float4*>(&As[k * FLDA + ty * 8 + 4]);
                *reinterpret_cast<float4*>(&b[0]) = *reinterpret_cast<float4*>(&Bs[k * FLDA + tx * 4]);
                *reinterpret_cast<float4*>(&b[4]) = *reinterpret_cast<float4*>(&Bs[k * FLDA + 64 + tx * 4]);
#pragma unroll
                for (int i = 0; i < 8; ++i)
#pragma unroll
                    for (int j = 0; j < 8; ++j)
                        acc[i][j] = fmaf(a[i], b[j], acc[i][j]);
            }
            __syncthreads();
        }

        if (tid < FBN) tinvS[tid] = tinv[tb + tid];
        __syncthreads();

#pragma unroll
        for (int cc = 0; cc < 4; ++cc) {
            const int g = cc >> 1;
            if ((tx >> 3) == (cc & 1)) {
                const int txl = tx & 7;
#pragma unroll
                for (int i = 0; i < 8; ++i) {
                    const int rrow = ty * 8 + i;
#pragma unroll
                    for (int j = 0; j < 4; ++j) {
                        const int colc = 4 * txl + j;
                        Ss[rrow * FLDSS + colc] = acc[i][g * 4 + j] * tinvS[cc * 32 + colc];
                    }
                }
            }
            __syncthreads();
            if (tid < FBM) {
#pragma unroll 4
                for (int c = 0; c < 32; ++c) {
                    const float v = Ss[tid * FLDSS + c];
                    if (v > t3) {
                        const int gi = tb + cc * 32 + c;
                        if (v > t0)      { t3=t2;i3=i2; t2=t1;i2=i1; t1=t0;i1=i0; t0=v;i0=gi; }
                        else if (v > t1) { t3=t2;i3=i2; t2=t1;i2=i1; t1=v;i1=gi; }
                        else if (v > t2) { t3=t2;i3=i2; t2=v;i2=gi; }
                        else             { t3=v;i3=gi; }
                    }
                }
            }
            __syncthreads();
        }
    }

    if (tid < FBM) {
        const int row = rb * FBM + tid;
        const size_t base = ((size_t)blockIdx.y * M + row) * 4;
        pval[base + 0] = t0; pval[base + 1] = t1; pval[base + 2] = t2; pval[base + 3] = t3;
        pidx[base + 0] = i0; pidx[base + 1] = i1; pidx[base + 2] = i2; pidx[base + 3] = i3;
    }
}

__global__ void merge_kernel(const float* __restrict__ pval, const int* __restrict__ pidx,
                             const float* __restrict__ T, float* __restrict__ out) {
    __shared__ float cv[FNS * 4];
    __shared__ int   ci[FNS * 4];
    __shared__ int   sel[4];
    const int r = blockIdx.x;
    const int tid = threadIdx.x;

    if (tid < FNS * 4) {
        const int s = tid >> 2, q = tid & 3;
        const size_t base = ((size_t)s * M + r) * 4 + q;
        cv[tid] = pval[base];
        ci[tid] = pidx[base];
    }
    __syncthreads();

    if (tid == 0) {
        float t0 = -INFINITY, t1 = -INFINITY, t2 = -INFINITY, t3 = -INFINITY;
        int   j0 = 0, j1 = 0, j2 = 0, j3 = 0;
        for (int c = 0; c < FNS * 4; ++c) {
            const float v = cv[c];
            if (v > t3) {
                const int gi = ci[c];
                if (v > t0)      { t3=t2;j3=j2; t2=t1;j2=j1; t1=t0;j1=j0; t0=v;j0=gi; }
                else if (v > t1) { t3=t2;j3=j2; t2=t1;j2=j1; t1=v;j1=gi; }
                else if (v > t2) { t3=t2;j3=j2; t2=v;j2=gi; }
                else             { t3=v;j3=gi; }
            }
        }
        sel[0] = j0; sel[1] = j1; sel[2] = j2; sel[3] = j3;
    }
    __syncthreads();

    const int d = tid * 4;
    float4 a = make_float4(0.f, 0.f, 0.f, 0.f);
#pragma unroll
    for (int q = 0; q < 4; ++q) {
        const float4 v = *reinterpret_cast<const float4*>(T + (size_t)sel[q] * KD + d);
        a.x += v.x; a.y += v.y; a.z += v.z; a.w += v.w;
    }
    a.x *= 0.25f; a.y *= 0.25f; a.z *= 0.25f; a.w *= 0.25f;
    *reinterpret_cast<float4*>(out + (size_t)r * KD + d) = a;
}

// ---------------------------------------------------------------------------
extern "C" void kernel_launch(void* const* d_in, const int* in_sizes, int n_in,
                              void* d_out, int out_size, void* d_ws, size_t ws_size,
                              hipStream_t stream) {
    const float* S = (const float*)d_in[0];   // [4096,1024]
    const float* T = (const float*)d_in[1];   // [65536,1024]
    float* out = (float*)d_out;               // [4096,1024]

    const size_t sz_tinv = (size_t)NTGT * 4;                 // 256 KB
    const size_t sz_Sq   = (size_t)M * KD;                   // 4 MB
    const size_t sz_Tq   = (size_t)NTGT * KD;                // 64 MB
    const size_t sz_cand = (size_t)M * NCAND * 4;            // 4 MB
    const size_t need = sz_tinv + sz_Sq + sz_Tq + sz_cand;   // ~72.3 MB

    if (ws_size >= need) {
        float*    tinv = (float*)d_ws;
        char*     Sq   = (char*)d_ws + sz_tinv;
        char*     Tq   = (char*)d_ws + sz_tinv + sz_Sq;
        uint32_t* cand = (uint32_t*)((char*)d_ws + sz_tinv + sz_Sq + sz_Tq);

        prep_targets<<<NTGT / 4, 256, 0, stream>>>(T, tinv, Tq);
        prep_source<<<M / 4, 256, 0, stream>>>(S, Sq);
        screen_kernel<<<dim3(M / BS, NS), 256, 0, stream>>>(Sq, Tq, cand);
        final_kernel<<<M, 256, 0, stream>>>(cand, S, T, tinv, out);
    } else {
        // round-1 fp32 fallback (~7 ms, proven correct)
        float* tinv = (float*)d_ws;
        float* pval = tinv + NTGT;
        int*   pidx = (int*)(pval + (size_t)FNS * M * 4);

        tinv_kernel<<<NTGT / 4, 256, 0, stream>>>(T, tinv);
        simtopk_kernel<<<dim3(M / FBM, FNS), 256, 0, stream>>>(S, T, tinv, pval, pidx);
        merge_kernel<<<M, 256, 0, stream>>>(pval, pidx, T, out);
    }
}